// Round 1
// baseline (4436.303 us; speedup 1.0000x reference)
//
#include <hip/hip_runtime.h>
#include <hip/hip_bf16.h>

typedef __bf16 bf16x8 __attribute__((ext_vector_type(8)));
typedef float  f32x4  __attribute__((ext_vector_type(4)));

#define MFMA16(a,b,c) __builtin_amdgcn_mfma_f32_16x16x32_bf16((a),(b),(c),0,0,0)

// ---------------- weight fp32 -> bf16 conversion (runs once per launch) -------------
__global__ void k_convert_weights(const float* __restrict__ wmsg,
                                  const float* __restrict__ wih,
                                  const float* __restrict__ whh,
                                  __bf16* __restrict__ o_msg,
                                  __bf16* __restrict__ o_ih,
                                  __bf16* __restrict__ o_hh,
                                  int n_msg, int n_ih, int n_hh) {
    int i = (blockIdx.x * 256 + threadIdx.x) * 4;
    int total = n_msg + n_ih + n_hh;
    #pragma unroll
    for (int j = 0; j < 4; ++j) {
        int idx = i + j;
        if (idx >= total) return;
        if (idx < n_msg)              o_msg[idx]               = (__bf16)wmsg[idx];
        else if (idx < n_msg + n_ih)  o_ih[idx - n_msg]        = (__bf16)wih[idx - n_msg];
        else                          o_hh[idx - n_msg - n_ih] = (__bf16)whh[idx - n_msg - n_ih];
    }
}

// ---------------- degree count ----------------
__global__ void k_deg(const int* __restrict__ dst, float* __restrict__ deg, int E) {
    int e = blockIdx.x * 256 + threadIdx.x;
    if (e < E) atomicAdd(&deg[dst[e]], 1.0f);
}

__global__ void k_invdeg(float* __restrict__ deg, int N) {
    int n = blockIdx.x * 256 + threadIdx.x;
    if (n < N) deg[n] = 1.0f / fmaxf(deg[n], 1.0f);
}

// ---------------- scatter-add of 128-wide rows ----------------
// srcdata rows indexed by gidx[e] (or e itself when gidx==nullptr), accumulated into acc[dst[e]].
// 32 threads per edge, float4 per thread.
__global__ void k_scatter_rows(const float* __restrict__ srcdata,
                               const int* __restrict__ gidx,
                               const int* __restrict__ dst,
                               float* __restrict__ acc, int E) {
    int idx = blockIdx.x * 256 + threadIdx.x;
    if (idx >= E * 32) return;
    int e  = idx >> 5;
    int c4 = (idx & 31) * 4;
    int row = gidx ? gidx[e] : e;
    const float4 v = *(const float4*)(srcdata + (size_t)row * 128 + c4);
    float* a = acc + (size_t)dst[e] * 128 + c4;
    atomicAdd(a + 0, v.x);
    atomicAdd(a + 1, v.y);
    atomicAdd(a + 2, v.z);
    atomicAdd(a + 3, v.w);
}

// ---------------- fused round: x-build + 3 GEMMs (bf16 MFMA) + GRU epilogue ----------
// Tile: 32 nodes per block, 4 waves (256 threads).
// GEMM1: a[32,256]  = x[32,384]  @ Wmsg^T   (wave w owns out cols [64w,64w+64))
// GEMM2: gi[32,384] = a[32,256]  @ Wih^T    (wave w owns cols {128c + 32w + [0,32) : c=0..2})
// GEMM3: gh[32,384] = hv[32,128] @ Whh^T    (same col split as GEMM2)
// The GEMM2/3 col split puts (o, o+128, o+256) in the same lane+reg -> GRU gates in registers.
__launch_bounds__(256)
__global__ void k_fused_round(
    const float* __restrict__ hv_in,     // [N,128]
    const float* __restrict__ hsrc_sum,  // [N,128]
    const float* __restrict__ he_sum,    // [N,128]
    const float* __restrict__ invdeg,    // [N]
    const __bf16* __restrict__ Wmsg,     // [256,384]
    const float* __restrict__ bmsg,      // [256]
    const __bf16* __restrict__ Wih,      // [384,256]
    const __bf16* __restrict__ Whh,      // [384,128]
    const float* __restrict__ bih,       // [384]
    const float* __restrict__ bhh,       // [384]
    float* __restrict__ hv_out, int N)
{
    __shared__ __bf16 xs[32][392];   // 384 + 8 pad (bank-spread)
    __shared__ __bf16 as[32][264];   // 256 + 8 pad

    const int tid = threadIdx.x;
    const int m0  = blockIdx.x * 32;

    // ---- build x = [hv | hsrc_sum*invdeg | he_sum*invdeg] as bf16 in LDS ----
    for (int idx = tid; idx < 32 * 96; idx += 256) {
        int row  = idx / 96;
        int seg  = idx % 96;
        int part = seg >> 5;          // 0: hv, 1: hsrc, 2: he
        int c4   = (seg & 31) * 4;
        int node = m0 + row;
        float4 v = make_float4(0.f, 0.f, 0.f, 0.f);
        if (node < N) {
            const float* base = (part == 0) ? hv_in : ((part == 1) ? hsrc_sum : he_sum);
            v = *(const float4*)(base + (size_t)node * 128 + c4);
            if (part) { float s = invdeg[node]; v.x *= s; v.y *= s; v.z *= s; v.w *= s; }
        }
        __bf16* p = &xs[row][part * 128 + c4];
        p[0] = (__bf16)v.x; p[1] = (__bf16)v.y; p[2] = (__bf16)v.z; p[3] = (__bf16)v.w;
    }
    __syncthreads();

    const int wave = tid >> 6;
    const int lane = tid & 63;
    const int lr = lane & 15;     // row/col-in-frag
    const int lk = lane >> 4;     // k-chunk (8 elems each)

    // ---- GEMM1: a = x @ Wmsg^T ----
    f32x4 acc1[2][4] = {};
    for (int k0 = 0; k0 < 384; k0 += 32) {
        bf16x8 a0 = *(const bf16x8*)&xs[lr][k0 + lk * 8];
        bf16x8 a1 = *(const bf16x8*)&xs[16 + lr][k0 + lk * 8];
        #pragma unroll
        for (int c = 0; c < 4; ++c) {
            const __bf16* wp = Wmsg + (size_t)(wave * 64 + c * 16 + lr) * 384 + k0 + lk * 8;
            bf16x8 b = *(const bf16x8*)wp;
            acc1[0][c] = MFMA16(a0, b, acc1[0][c]);
            acc1[1][c] = MFMA16(a1, b, acc1[1][c]);
        }
    }
    // write a (+bias) to LDS as bf16
    #pragma unroll
    for (int mf = 0; mf < 2; ++mf) {
        #pragma unroll
        for (int c = 0; c < 4; ++c) {
            int n = wave * 64 + c * 16 + lr;
            float bias = bmsg[n];
            #pragma unroll
            for (int r = 0; r < 4; ++r) {
                int m = mf * 16 + lk * 4 + r;
                as[m][n] = (__bf16)(acc1[mf][c][r] + bias);
            }
        }
    }
    __syncthreads();

    // ---- GEMM2: gi = a @ Wih^T ----
    f32x4 acc2[2][6] = {};
    for (int k0 = 0; k0 < 256; k0 += 32) {
        bf16x8 a0 = *(const bf16x8*)&as[lr][k0 + lk * 8];
        bf16x8 a1 = *(const bf16x8*)&as[16 + lr][k0 + lk * 8];
        #pragma unroll
        for (int q = 0; q < 6; ++q) {
            int o = (q >> 1) * 128 + wave * 32 + (q & 1) * 16 + lr;
            bf16x8 b = *(const bf16x8*)(Wih + (size_t)o * 256 + k0 + lk * 8);
            acc2[0][q] = MFMA16(a0, b, acc2[0][q]);
            acc2[1][q] = MFMA16(a1, b, acc2[1][q]);
        }
    }

    // ---- GEMM3: gh = hv @ Whh^T  (hv bf16 == xs[:,0:128]) ----
    f32x4 acc3[2][6] = {};
    for (int k0 = 0; k0 < 128; k0 += 32) {
        bf16x8 a0 = *(const bf16x8*)&xs[lr][k0 + lk * 8];
        bf16x8 a1 = *(const bf16x8*)&xs[16 + lr][k0 + lk * 8];
        #pragma unroll
        for (int q = 0; q < 6; ++q) {
            int o = (q >> 1) * 128 + wave * 32 + (q & 1) * 16 + lr;
            bf16x8 b = *(const bf16x8*)(Whh + (size_t)o * 128 + k0 + lk * 8);
            acc3[0][q] = MFMA16(a0, b, acc3[0][q]);
            acc3[1][q] = MFMA16(a1, b, acc3[1][q]);
        }
    }

    // ---- GRU epilogue (all in registers; r/z/n chunks share lane+reg) ----
    #pragma unroll
    for (int mf = 0; mf < 2; ++mf) {
        #pragma unroll
        for (int j = 0; j < 2; ++j) {
            int hcol = wave * 32 + j * 16 + lr;   // h index in [0,128)
            float b_ir = bih[hcol],       b_hr = bhh[hcol];
            float b_iz = bih[128 + hcol], b_hz = bhh[128 + hcol];
            float b_in = bih[256 + hcol], b_hn = bhh[256 + hcol];
            #pragma unroll
            for (int r = 0; r < 4; ++r) {
                int m = mf * 16 + lk * 4 + r;
                int node = m0 + m;
                if (node < N) {
                    float ir = acc2[mf][0 + j][r] + b_ir, hr = acc3[mf][0 + j][r] + b_hr;
                    float iz = acc2[mf][2 + j][r] + b_iz, hz = acc3[mf][2 + j][r] + b_hz;
                    float in_ = acc2[mf][4 + j][r] + b_in, hn = acc3[mf][4 + j][r] + b_hn;
                    float rg = 1.f / (1.f + __expf(-(ir + hr)));
                    float zg = 1.f / (1.f + __expf(-(iz + hz)));
                    float ng = tanhf(in_ + rg * hn);
                    float hold = hv_in[(size_t)node * 128 + hcol];
                    hv_out[(size_t)node * 128 + hcol] = (1.f - zg) * ng + zg * hold;
                }
            }
        }
    }
}

extern "C" void kernel_launch(void* const* d_in, const int* in_sizes, int n_in,
                              void* d_out, int out_size, void* d_ws, size_t ws_size,
                              hipStream_t stream)
{
    const float* hv   = (const float*)d_in[0];
    const float* he   = (const float*)d_in[1];
    const int*   src  = (const int*)d_in[2];
    const int*   dst  = (const int*)d_in[3];
    const float* Wmsg = (const float*)d_in[4];
    const float* bmsg = (const float*)d_in[5];
    const float* Wih  = (const float*)d_in[6];
    const float* Whh  = (const float*)d_in[7];
    const float* bih  = (const float*)d_in[8];
    const float* bhh  = (const float*)d_in[9];

    const int H = 128;
    const int N = in_sizes[0] / H;
    const int E = in_sizes[2];

    float* ws       = (float*)d_ws;
    float* he_sum   = ws;
    float* hsrc_sum = ws + (size_t)N * H;
    float* deg      = ws + (size_t)2 * N * H;
    size_t wboff    = ((size_t)2 * N * H + (size_t)N + 7) & ~(size_t)7;
    __bf16* wmsg_bf = (__bf16*)(ws + wboff);
    __bf16* wih_bf  = wmsg_bf + 2 * 256 * 384;
    __bf16* whh_bf  = wih_bf  + 2 * 384 * 256;

    // zero accumulators (he_sum, hsrc_sum, deg are contiguous)
    hipMemsetAsync(ws, 0, ((size_t)2 * N * H + N) * sizeof(float), stream);

    const int n_msg = 2 * 256 * 384, n_ih = 2 * 384 * 256, n_hh = 2 * 384 * 128;
    const int tot = n_msg + n_ih + n_hh;
    k_convert_weights<<<(tot / 4 + 255) / 256, 256, 0, stream>>>(
        Wmsg, Wih, Whh, wmsg_bf, wih_bf, whh_bf, n_msg, n_ih, n_hh);

    k_deg<<<(E + 255) / 256, 256, 0, stream>>>(dst, deg, E);
    k_scatter_rows<<<(E * 32 + 255) / 256, 256, 0, stream>>>(he, nullptr, dst, he_sum, E);
    k_invdeg<<<(N + 255) / 256, 256, 0, stream>>>(deg, N);

    float* out = (float*)d_out;
    for (int t = 0; t < 2; ++t) {
        const float* hv_cur = (t == 0) ? hv : out;
        if (t > 0) hipMemsetAsync(hsrc_sum, 0, (size_t)N * H * sizeof(float), stream);
        k_scatter_rows<<<(E * 32 + 255) / 256, 256, 0, stream>>>(hv_cur, src, dst, hsrc_sum, E);
        k_fused_round<<<(N + 31) / 32, 256, 0, stream>>>(
            hv_cur, hsrc_sum, he_sum, deg,
            wmsg_bf + (size_t)t * 256 * 384, bmsg + (size_t)t * 256,
            wih_bf  + (size_t)t * 384 * 256, whh_bf + (size_t)t * 384 * 128,
            bih + (size_t)t * 384, bhh + (size_t)t * 384,
            out, N);
    }
}

// Round 2
// 795.030 us; speedup vs baseline: 5.5800x; 5.5800x over previous
//
#include <hip/hip_runtime.h>
#include <hip/hip_bf16.h>

typedef __bf16 bf16x8 __attribute__((ext_vector_type(8)));
typedef __bf16 bf16x2 __attribute__((ext_vector_type(2)));
typedef float  f32x4  __attribute__((ext_vector_type(4)));

#define MFMA16(a,b,c) __builtin_amdgcn_mfma_f32_16x16x32_bf16((a),(b),(c),0,0,0)

// ---------------- weight fp32 -> bf16 conversion ----------------
__global__ void k_convert_weights(const float* __restrict__ wmsg,
                                  const float* __restrict__ wih,
                                  const float* __restrict__ whh,
                                  __bf16* __restrict__ o_msg,
                                  __bf16* __restrict__ o_ih,
                                  __bf16* __restrict__ o_hh,
                                  int n_msg, int n_ih, int n_hh) {
    int i = (blockIdx.x * 256 + threadIdx.x) * 4;
    int total = n_msg + n_ih + n_hh;
    #pragma unroll
    for (int j = 0; j < 4; ++j) {
        int idx = i + j;
        if (idx >= total) return;
        if (idx < n_msg)              o_msg[idx]               = (__bf16)wmsg[idx];
        else if (idx < n_msg + n_ih)  o_ih[idx - n_msg]        = (__bf16)wih[idx - n_msg];
        else                          o_hh[idx - n_msg - n_ih] = (__bf16)whh[idx - n_msg - n_ih];
    }
}

// ---------------- CSR build ----------------
__global__ void k_deg(const int* __restrict__ dst, int* __restrict__ degi, int E) {
    int e = blockIdx.x * 256 + threadIdx.x;
    if (e < E) atomicAdd(&degi[dst[e]], 1);
}

// single-block exclusive scan over degi -> off[0..N], zero cnt
__global__ void k_scan(const int* __restrict__ degi, int* __restrict__ off,
                       int* __restrict__ cnt, int N) {
    __shared__ int warp_tot[4];
    __shared__ int s_running;
    if (threadIdx.x == 0) s_running = 0;
    const int lane = threadIdx.x & 63;
    const int w    = threadIdx.x >> 6;
    __syncthreads();
    for (int base = 0; base < N; base += 256) {
        int i = base + (int)threadIdx.x;
        int v = (i < N) ? degi[i] : 0;
        int incl = v;
        #pragma unroll
        for (int d = 1; d < 64; d <<= 1) {
            int t = __shfl_up(incl, d, 64);
            if (lane >= d) incl += t;
        }
        if (lane == 63) warp_tot[w] = incl;
        __syncthreads();
        int run = s_running;
        int woff = 0;
        #pragma unroll
        for (int k = 0; k < 4; ++k) if (k < w) woff += warp_tot[k];
        if (i < N) { off[i] = run + woff + incl - v; cnt[i] = 0; }
        int tot = warp_tot[0] + warp_tot[1] + warp_tot[2] + warp_tot[3];
        __syncthreads();
        if (threadIdx.x == 0) s_running = run + tot;
    }
    __syncthreads();
    if (threadIdx.x == 0) off[N] = s_running;
}

__global__ void k_bucket(const int* __restrict__ src, const int* __restrict__ dst,
                         const int* __restrict__ off, int* __restrict__ cnt,
                         int* __restrict__ src_sorted, int* __restrict__ eid_sorted, int E) {
    int e = blockIdx.x * 256 + threadIdx.x;
    if (e < E) {
        int d = dst[e];
        int p = off[d] + atomicAdd(&cnt[d], 1);
        src_sorted[p] = src[e];
        eid_sorted[p] = e;
    }
}

// ---------------- gather-mean: one wave per node, lane owns float2 cols ----------------
__global__ void k_gather_mean(const float* __restrict__ rows,   // [R,128] f32 source table
                              const int* __restrict__ idx,      // CSR-sorted row indices
                              const int* __restrict__ off,
                              __bf16* __restrict__ mean_out,    // [N,128] bf16
                              int N) {
    int node = blockIdx.x * 4 + ((int)threadIdx.x >> 6);
    if (node >= N) return;
    int lane = (int)threadIdx.x & 63;
    int beg = off[node], end = off[node + 1];
    float ax = 0.f, ay = 0.f, bx = 0.f, by = 0.f;
    int p = beg;
    for (; p + 1 < end; p += 2) {
        int r0 = idx[p], r1 = idx[p + 1];
        float2 v0 = *(const float2*)(rows + (size_t)r0 * 128 + lane * 2);
        float2 v1 = *(const float2*)(rows + (size_t)r1 * 128 + lane * 2);
        ax += v0.x; ay += v0.y; bx += v1.x; by += v1.y;
    }
    if (p < end) {
        int r0 = idx[p];
        float2 v0 = *(const float2*)(rows + (size_t)r0 * 128 + lane * 2);
        ax += v0.x; ay += v0.y;
    }
    ax += bx; ay += by;
    float s = 1.0f / fmaxf((float)(end - beg), 1.0f);
    bf16x2 o; o[0] = (__bf16)(ax * s); o[1] = (__bf16)(ay * s);
    *(bf16x2*)(mean_out + (size_t)node * 128 + lane * 2) = o;
}

// ---------------- fused round: x-build + 3 GEMMs (bf16 MFMA) + GRU epilogue ----------
__launch_bounds__(256)
__global__ void k_fused_round(
    const float* __restrict__ hv_in,       // [N,128] f32
    const __bf16* __restrict__ hsrc_mean,  // [N,128] bf16
    const __bf16* __restrict__ he_mean,    // [N,128] bf16
    const __bf16* __restrict__ Wmsg,       // [256,384]
    const float* __restrict__ bmsg,        // [256]
    const __bf16* __restrict__ Wih,        // [384,256]
    const __bf16* __restrict__ Whh,        // [384,128]
    const float* __restrict__ bih,         // [384]
    const float* __restrict__ bhh,         // [384]
    float* __restrict__ hv_out, int N)
{
    __shared__ __bf16 xs[32][392];   // 384 + 8 pad
    __shared__ __bf16 as[32][264];   // 256 + 8 pad

    const int tid = threadIdx.x;
    const int m0  = blockIdx.x * 32;

    // ---- build x = [hv | hsrc_mean | he_mean] as bf16 in LDS ----
    // hv part: f32 -> bf16
    for (int idx = tid; idx < 32 * 32; idx += 256) {   // 32 rows x 32 float4 chunks
        int row = idx >> 5, c4 = (idx & 31) * 4;
        int node = m0 + row;
        float4 v = make_float4(0.f, 0.f, 0.f, 0.f);
        if (node < N) v = *(const float4*)(hv_in + (size_t)node * 128 + c4);
        __bf16* p = &xs[row][c4];
        p[0] = (__bf16)v.x; p[1] = (__bf16)v.y; p[2] = (__bf16)v.z; p[3] = (__bf16)v.w;
    }
    // mean parts: bf16 copy, 8-wide
    for (int idx = tid; idx < 32 * 32; idx += 256) {   // 32 rows x (2 parts x 16 chunks)
        int row = idx >> 5;
        int seg = idx & 31;
        int part = seg >> 4;           // 0: hsrc, 1: he
        int c8 = (seg & 15) * 8;
        int node = m0 + row;
        const __bf16* base = part ? he_mean : hsrc_mean;
        bf16x8 v = {};
        if (node < N) v = *(const bf16x8*)(base + (size_t)node * 128 + c8);
        *(bf16x8*)&xs[row][128 + part * 128 + c8] = v;
    }
    __syncthreads();

    const int wave = tid >> 6;
    const int lane = tid & 63;
    const int lr = lane & 15;
    const int lk = lane >> 4;

    // ---- GEMM1: a = x @ Wmsg^T ----
    f32x4 acc1[2][4] = {};
    for (int k0 = 0; k0 < 384; k0 += 32) {
        bf16x8 a0 = *(const bf16x8*)&xs[lr][k0 + lk * 8];
        bf16x8 a1 = *(const bf16x8*)&xs[16 + lr][k0 + lk * 8];
        #pragma unroll
        for (int c = 0; c < 4; ++c) {
            const __bf16* wp = Wmsg + (size_t)(wave * 64 + c * 16 + lr) * 384 + k0 + lk * 8;
            bf16x8 b = *(const bf16x8*)wp;
            acc1[0][c] = MFMA16(a0, b, acc1[0][c]);
            acc1[1][c] = MFMA16(a1, b, acc1[1][c]);
        }
    }
    #pragma unroll
    for (int mf = 0; mf < 2; ++mf) {
        #pragma unroll
        for (int c = 0; c < 4; ++c) {
            int n = wave * 64 + c * 16 + lr;
            float bias = bmsg[n];
            #pragma unroll
            for (int r = 0; r < 4; ++r) {
                int m = mf * 16 + lk * 4 + r;
                as[m][n] = (__bf16)(acc1[mf][c][r] + bias);
            }
        }
    }
    __syncthreads();

    // ---- GEMM2: gi = a @ Wih^T ----
    f32x4 acc2[2][6] = {};
    for (int k0 = 0; k0 < 256; k0 += 32) {
        bf16x8 a0 = *(const bf16x8*)&as[lr][k0 + lk * 8];
        bf16x8 a1 = *(const bf16x8*)&as[16 + lr][k0 + lk * 8];
        #pragma unroll
        for (int q = 0; q < 6; ++q) {
            int o = (q >> 1) * 128 + wave * 32 + (q & 1) * 16 + lr;
            bf16x8 b = *(const bf16x8*)(Wih + (size_t)o * 256 + k0 + lk * 8);
            acc2[0][q] = MFMA16(a0, b, acc2[0][q]);
            acc2[1][q] = MFMA16(a1, b, acc2[1][q]);
        }
    }

    // ---- GEMM3: gh = hv @ Whh^T ----
    f32x4 acc3[2][6] = {};
    for (int k0 = 0; k0 < 128; k0 += 32) {
        bf16x8 a0 = *(const bf16x8*)&xs[lr][k0 + lk * 8];
        bf16x8 a1 = *(const bf16x8*)&xs[16 + lr][k0 + lk * 8];
        #pragma unroll
        for (int q = 0; q < 6; ++q) {
            int o = (q >> 1) * 128 + wave * 32 + (q & 1) * 16 + lr;
            bf16x8 b = *(const bf16x8*)(Whh + (size_t)o * 128 + k0 + lk * 8);
            acc3[0][q] = MFMA16(a0, b, acc3[0][q]);
            acc3[1][q] = MFMA16(a1, b, acc3[1][q]);
        }
    }

    // ---- GRU epilogue ----
    #pragma unroll
    for (int mf = 0; mf < 2; ++mf) {
        #pragma unroll
        for (int j = 0; j < 2; ++j) {
            int hcol = wave * 32 + j * 16 + lr;
            float b_ir = bih[hcol],       b_hr = bhh[hcol];
            float b_iz = bih[128 + hcol], b_hz = bhh[128 + hcol];
            float b_in = bih[256 + hcol], b_hn = bhh[256 + hcol];
            #pragma unroll
            for (int r = 0; r < 4; ++r) {
                int m = mf * 16 + lk * 4 + r;
                int node = m0 + m;
                if (node < N) {
                    float ir = acc2[mf][0 + j][r] + b_ir, hr = acc3[mf][0 + j][r] + b_hr;
                    float iz = acc2[mf][2 + j][r] + b_iz, hz = acc3[mf][2 + j][r] + b_hz;
                    float in_ = acc2[mf][4 + j][r] + b_in, hn = acc3[mf][4 + j][r] + b_hn;
                    float rg = 1.f / (1.f + __expf(-(ir + hr)));
                    float zg = 1.f / (1.f + __expf(-(iz + hz)));
                    float ng = tanhf(in_ + rg * hn);
                    float hold = hv_in[(size_t)node * 128 + hcol];
                    hv_out[(size_t)node * 128 + hcol] = (1.f - zg) * ng + zg * hold;
                }
            }
        }
    }
}

extern "C" void kernel_launch(void* const* d_in, const int* in_sizes, int n_in,
                              void* d_out, int out_size, void* d_ws, size_t ws_size,
                              hipStream_t stream)
{
    const float* hv   = (const float*)d_in[0];
    const float* he   = (const float*)d_in[1];
    const int*   src  = (const int*)d_in[2];
    const int*   dst  = (const int*)d_in[3];
    const float* Wmsg = (const float*)d_in[4];
    const float* bmsg = (const float*)d_in[5];
    const float* Wih  = (const float*)d_in[6];
    const float* Whh  = (const float*)d_in[7];
    const float* bih  = (const float*)d_in[8];
    const float* bhh  = (const float*)d_in[9];

    const int H = 128;
    const int N = in_sizes[0] / H;
    const int E = in_sizes[2];

    // ---- workspace layout ----
    char* w = (char*)d_ws;
    __bf16* he_mean   = (__bf16*)w;  w += (size_t)N * H * 2;
    __bf16* hsrc_mean = (__bf16*)w;  w += (size_t)N * H * 2;
    int* degi  = (int*)w;  w += (size_t)N * 4;
    int* off   = (int*)w;  w += (size_t)(N + 1) * 4;
    int* cnt   = (int*)w;  w += (size_t)N * 4;
    int* src_s = (int*)w;  w += (size_t)E * 4;
    int* eid_s = (int*)w;  w += (size_t)E * 4;
    w = (char*)(((uintptr_t)w + 15) & ~(uintptr_t)15);
    __bf16* wmsg_bf = (__bf16*)w;
    __bf16* wih_bf  = wmsg_bf + 2 * 256 * 384;
    __bf16* whh_bf  = wih_bf  + 2 * 384 * 256;

    hipMemsetAsync(degi, 0, (size_t)N * 4, stream);

    const int n_msg = 2 * 256 * 384, n_ih = 2 * 384 * 256, n_hh = 2 * 384 * 128;
    const int tot = n_msg + n_ih + n_hh;
    k_convert_weights<<<(tot / 4 + 255) / 256, 256, 0, stream>>>(
        Wmsg, Wih, Whh, wmsg_bf, wih_bf, whh_bf, n_msg, n_ih, n_hh);

    // ---- CSR build ----
    k_deg<<<(E + 255) / 256, 256, 0, stream>>>(dst, degi, E);
    k_scan<<<1, 256, 0, stream>>>(degi, off, cnt, N);
    k_bucket<<<(E + 255) / 256, 256, 0, stream>>>(src, dst, off, cnt, src_s, eid_s, E);

    // ---- mean_he (once) ----
    k_gather_mean<<<(N + 3) / 4, 256, 0, stream>>>(he, eid_s, off, he_mean, N);

    float* out = (float*)d_out;
    for (int t = 0; t < 2; ++t) {
        const float* hv_cur = (t == 0) ? hv : out;
        k_gather_mean<<<(N + 3) / 4, 256, 0, stream>>>(hv_cur, src_s, off, hsrc_mean, N);
        k_fused_round<<<(N + 31) / 32, 256, 0, stream>>>(
            hv_cur, hsrc_mean, he_mean,
            wmsg_bf + (size_t)t * 256 * 384, bmsg + (size_t)t * 256,
            wih_bf  + (size_t)t * 384 * 256, whh_bf + (size_t)t * 384 * 128,
            bih + (size_t)t * 384, bhh + (size_t)t * 384,
            out, N);
    }
}

// Round 3
// 587.957 us; speedup vs baseline: 7.5453x; 1.3522x over previous
//
#include <hip/hip_runtime.h>
#include <hip/hip_bf16.h>

typedef __bf16 bf16x8 __attribute__((ext_vector_type(8)));
typedef __bf16 bf16x2 __attribute__((ext_vector_type(2)));
typedef float  f32x4  __attribute__((ext_vector_type(4)));

#define MFMA16(a,b,c) __builtin_amdgcn_mfma_f32_16x16x32_bf16((a),(b),(c),0,0,0)

// ---------------- weight fp32 -> bf16 conversion ----------------
__global__ void k_convert_weights(const float* __restrict__ wmsg,
                                  const float* __restrict__ wih,
                                  const float* __restrict__ whh,
                                  __bf16* __restrict__ o_msg,
                                  __bf16* __restrict__ o_ih,
                                  __bf16* __restrict__ o_hh,
                                  int n_msg, int n_ih, int n_hh) {
    int i = (blockIdx.x * 256 + threadIdx.x) * 4;
    int total = n_msg + n_ih + n_hh;
    #pragma unroll
    for (int j = 0; j < 4; ++j) {
        int idx = i + j;
        if (idx >= total) return;
        if (idx < n_msg)              o_msg[idx]               = (__bf16)wmsg[idx];
        else if (idx < n_msg + n_ih)  o_ih[idx - n_msg]        = (__bf16)wih[idx - n_msg];
        else                          o_hh[idx - n_msg - n_ih] = (__bf16)whh[idx - n_msg - n_ih];
    }
}

// ---------------- CSR build ----------------
__global__ void k_deg(const int* __restrict__ dst, int* __restrict__ degi, int E) {
    int e = blockIdx.x * 256 + threadIdx.x;
    if (e < E) atomicAdd(&degi[dst[e]], 1);
}

// per-wave prefix + one atomic per wave; offsets disjoint (not monotone - fine)
__global__ void k_alloc(const int* __restrict__ degi, int* __restrict__ off,
                        int* __restrict__ cnt, int* __restrict__ counter, int N) {
    int i = blockIdx.x * 256 + threadIdx.x;
    int lane = (int)threadIdx.x & 63;
    int v = (i < N) ? degi[i] : 0;
    int incl = v;
    #pragma unroll
    for (int d = 1; d < 64; d <<= 1) {
        int t = __shfl_up(incl, d, 64);
        if (lane >= d) incl += t;
    }
    int base = 0;
    if (lane == 63) base = atomicAdd(counter, incl);
    base = __shfl(base, 63, 64);
    if (i < N) { off[i] = base + incl - v; cnt[i] = 0; }
}

__global__ void k_bucket(const int* __restrict__ src, const int* __restrict__ dst,
                         const int* __restrict__ off, int* __restrict__ cnt,
                         int2* __restrict__ pairs, int E) {
    int e = blockIdx.x * 256 + threadIdx.x;
    if (e < E) {
        int d = dst[e];
        int p = off[d] + atomicAdd(&cnt[d], 1);
        pairs[p] = make_int2(src[e], e);   // (src node, edge id)
    }
}

// ---------------- round-1 gather: mean(hv[src]) AND mean(he[eid]) in one edge pass ----
__global__ void k_gather_both(const float* __restrict__ hv, const float* __restrict__ he,
                              const int2* __restrict__ pairs,
                              const int* __restrict__ off, const int* __restrict__ degi,
                              __bf16* __restrict__ hsrc_mean, __bf16* __restrict__ he_mean,
                              int N) {
    int node = blockIdx.x * 4 + ((int)threadIdx.x >> 6);
    if (node >= N) return;
    int lane = (int)threadIdx.x & 63;
    int beg = off[node], deg = degi[node];
    int end = beg + deg;
    float h0x = 0.f, h0y = 0.f, h1x = 0.f, h1y = 0.f;
    float e0x = 0.f, e0y = 0.f, e1x = 0.f, e1y = 0.f;
    int p = beg;
    for (; p + 1 < end; p += 2) {
        int2 a = pairs[p], b = pairs[p + 1];
        float2 v0 = *(const float2*)(hv + (size_t)a.x * 128 + lane * 2);
        float2 w0 = *(const float2*)(he + (size_t)a.y * 128 + lane * 2);
        float2 v1 = *(const float2*)(hv + (size_t)b.x * 128 + lane * 2);
        float2 w1 = *(const float2*)(he + (size_t)b.y * 128 + lane * 2);
        h0x += v0.x; h0y += v0.y; h1x += v1.x; h1y += v1.y;
        e0x += w0.x; e0y += w0.y; e1x += w1.x; e1y += w1.y;
    }
    if (p < end) {
        int2 a = pairs[p];
        float2 v0 = *(const float2*)(hv + (size_t)a.x * 128 + lane * 2);
        float2 w0 = *(const float2*)(he + (size_t)a.y * 128 + lane * 2);
        h0x += v0.x; h0y += v0.y; e0x += w0.x; e0y += w0.y;
    }
    float s = 1.0f / fmaxf((float)deg, 1.0f);
    bf16x2 oh; oh[0] = (__bf16)((h0x + h1x) * s); oh[1] = (__bf16)((h0y + h1y) * s);
    bf16x2 oe; oe[0] = (__bf16)((e0x + e1x) * s); oe[1] = (__bf16)((e0y + e1y) * s);
    *(bf16x2*)(hsrc_mean + (size_t)node * 128 + lane * 2) = oh;
    *(bf16x2*)(he_mean   + (size_t)node * 128 + lane * 2) = oe;
}

// ---------------- round-2 gather: mean(hv[src]) only ----------------
__global__ void k_gather_hv(const float* __restrict__ hv, const int2* __restrict__ pairs,
                            const int* __restrict__ off, const int* __restrict__ degi,
                            __bf16* __restrict__ hsrc_mean, int N) {
    int node = blockIdx.x * 4 + ((int)threadIdx.x >> 6);
    if (node >= N) return;
    int lane = (int)threadIdx.x & 63;
    int beg = off[node], deg = degi[node];
    int end = beg + deg;
    float a0x = 0.f, a0y = 0.f, a1x = 0.f, a1y = 0.f;
    float a2x = 0.f, a2y = 0.f, a3x = 0.f, a3y = 0.f;
    int p = beg;
    for (; p + 3 < end; p += 4) {
        int2 pa = pairs[p], pb = pairs[p + 1], pc = pairs[p + 2], pd = pairs[p + 3];
        float2 v0 = *(const float2*)(hv + (size_t)pa.x * 128 + lane * 2);
        float2 v1 = *(const float2*)(hv + (size_t)pb.x * 128 + lane * 2);
        float2 v2 = *(const float2*)(hv + (size_t)pc.x * 128 + lane * 2);
        float2 v3 = *(const float2*)(hv + (size_t)pd.x * 128 + lane * 2);
        a0x += v0.x; a0y += v0.y; a1x += v1.x; a1y += v1.y;
        a2x += v2.x; a2y += v2.y; a3x += v3.x; a3y += v3.y;
    }
    for (; p < end; ++p) {
        int2 pa = pairs[p];
        float2 v0 = *(const float2*)(hv + (size_t)pa.x * 128 + lane * 2);
        a0x += v0.x; a0y += v0.y;
    }
    float s = 1.0f / fmaxf((float)deg, 1.0f);
    bf16x2 o; o[0] = (__bf16)((a0x + a1x + a2x + a3x) * s);
    o[1] = (__bf16)((a0y + a1y + a2y + a3y) * s);
    *(bf16x2*)(hsrc_mean + (size_t)node * 128 + lane * 2) = o;
}

// ---------------- fused round: x-build + 3 GEMMs (bf16 MFMA) + GRU epilogue ----------
__launch_bounds__(256)
__global__ void k_fused_round(
    const float* __restrict__ hv_in,       // [N,128] f32
    const __bf16* __restrict__ hsrc_mean,  // [N,128] bf16
    const __bf16* __restrict__ he_mean,    // [N,128] bf16
    const __bf16* __restrict__ Wmsg,       // [256,384]
    const float* __restrict__ bmsg,        // [256]
    const __bf16* __restrict__ Wih,        // [384,256]
    const __bf16* __restrict__ Whh,        // [384,128]
    const float* __restrict__ bih,         // [384]
    const float* __restrict__ bhh,         // [384]
    float* __restrict__ hv_out, int N)
{
    __shared__ __bf16 xs[32][392];   // 384 + 8 pad
    __shared__ __bf16 as[32][264];   // 256 + 8 pad

    const int tid = threadIdx.x;
    const int m0  = blockIdx.x * 32;

    for (int idx = tid; idx < 32 * 32; idx += 256) {
        int row = idx >> 5, c4 = (idx & 31) * 4;
        int node = m0 + row;
        float4 v = make_float4(0.f, 0.f, 0.f, 0.f);
        if (node < N) v = *(const float4*)(hv_in + (size_t)node * 128 + c4);
        __bf16* p = &xs[row][c4];
        p[0] = (__bf16)v.x; p[1] = (__bf16)v.y; p[2] = (__bf16)v.z; p[3] = (__bf16)v.w;
    }
    for (int idx = tid; idx < 32 * 32; idx += 256) {
        int row = idx >> 5;
        int seg = idx & 31;
        int part = seg >> 4;
        int c8 = (seg & 15) * 8;
        int node = m0 + row;
        const __bf16* base = part ? he_mean : hsrc_mean;
        bf16x8 v = {};
        if (node < N) v = *(const bf16x8*)(base + (size_t)node * 128 + c8);
        *(bf16x8*)&xs[row][128 + part * 128 + c8] = v;
    }
    __syncthreads();

    const int wave = tid >> 6;
    const int lane = tid & 63;
    const int lr = lane & 15;
    const int lk = lane >> 4;

    // ---- GEMM1: a = x @ Wmsg^T ----
    f32x4 acc1[2][4] = {};
    for (int k0 = 0; k0 < 384; k0 += 32) {
        bf16x8 a0 = *(const bf16x8*)&xs[lr][k0 + lk * 8];
        bf16x8 a1 = *(const bf16x8*)&xs[16 + lr][k0 + lk * 8];
        #pragma unroll
        for (int c = 0; c < 4; ++c) {
            const __bf16* wp = Wmsg + (size_t)(wave * 64 + c * 16 + lr) * 384 + k0 + lk * 8;
            bf16x8 b = *(const bf16x8*)wp;
            acc1[0][c] = MFMA16(a0, b, acc1[0][c]);
            acc1[1][c] = MFMA16(a1, b, acc1[1][c]);
        }
    }
    #pragma unroll
    for (int mf = 0; mf < 2; ++mf) {
        #pragma unroll
        for (int c = 0; c < 4; ++c) {
            int n = wave * 64 + c * 16 + lr;
            float bias = bmsg[n];
            #pragma unroll
            for (int r = 0; r < 4; ++r) {
                int m = mf * 16 + lk * 4 + r;
                as[m][n] = (__bf16)(acc1[mf][c][r] + bias);
            }
        }
    }
    __syncthreads();

    // ---- GEMM2: gi = a @ Wih^T ----
    f32x4 acc2[2][6] = {};
    for (int k0 = 0; k0 < 256; k0 += 32) {
        bf16x8 a0 = *(const bf16x8*)&as[lr][k0 + lk * 8];
        bf16x8 a1 = *(const bf16x8*)&as[16 + lr][k0 + lk * 8];
        #pragma unroll
        for (int q = 0; q < 6; ++q) {
            int o = (q >> 1) * 128 + wave * 32 + (q & 1) * 16 + lr;
            bf16x8 b = *(const bf16x8*)(Wih + (size_t)o * 256 + k0 + lk * 8);
            acc2[0][q] = MFMA16(a0, b, acc2[0][q]);
            acc2[1][q] = MFMA16(a1, b, acc2[1][q]);
        }
    }

    // ---- GEMM3: gh = hv @ Whh^T ----
    f32x4 acc3[2][6] = {};
    for (int k0 = 0; k0 < 128; k0 += 32) {
        bf16x8 a0 = *(const bf16x8*)&xs[lr][k0 + lk * 8];
        bf16x8 a1 = *(const bf16x8*)&xs[16 + lr][k0 + lk * 8];
        #pragma unroll
        for (int q = 0; q < 6; ++q) {
            int o = (q >> 1) * 128 + wave * 32 + (q & 1) * 16 + lr;
            bf16x8 b = *(const bf16x8*)(Whh + (size_t)o * 128 + k0 + lk * 8);
            acc3[0][q] = MFMA16(a0, b, acc3[0][q]);
            acc3[1][q] = MFMA16(a1, b, acc3[1][q]);
        }
    }

    // ---- GRU epilogue ----
    #pragma unroll
    for (int mf = 0; mf < 2; ++mf) {
        #pragma unroll
        for (int j = 0; j < 2; ++j) {
            int hcol = wave * 32 + j * 16 + lr;
            float b_ir = bih[hcol],       b_hr = bhh[hcol];
            float b_iz = bih[128 + hcol], b_hz = bhh[128 + hcol];
            float b_in = bih[256 + hcol], b_hn = bhh[256 + hcol];
            #pragma unroll
            for (int r = 0; r < 4; ++r) {
                int m = mf * 16 + lk * 4 + r;
                int node = m0 + m;
                if (node < N) {
                    float ir = acc2[mf][0 + j][r] + b_ir, hr = acc3[mf][0 + j][r] + b_hr;
                    float iz = acc2[mf][2 + j][r] + b_iz, hz = acc3[mf][2 + j][r] + b_hz;
                    float in_ = acc2[mf][4 + j][r] + b_in, hn = acc3[mf][4 + j][r] + b_hn;
                    float rg = 1.f / (1.f + __expf(-(ir + hr)));
                    float zg = 1.f / (1.f + __expf(-(iz + hz)));
                    float ng = tanhf(in_ + rg * hn);
                    float hold = hv_in[(size_t)node * 128 + hcol];
                    hv_out[(size_t)node * 128 + hcol] = (1.f - zg) * ng + zg * hold;
                }
            }
        }
    }
}

extern "C" void kernel_launch(void* const* d_in, const int* in_sizes, int n_in,
                              void* d_out, int out_size, void* d_ws, size_t ws_size,
                              hipStream_t stream)
{
    const float* hv   = (const float*)d_in[0];
    const float* he   = (const float*)d_in[1];
    const int*   src  = (const int*)d_in[2];
    const int*   dst  = (const int*)d_in[3];
    const float* Wmsg = (const float*)d_in[4];
    const float* bmsg = (const float*)d_in[5];
    const float* Wih  = (const float*)d_in[6];
    const float* Whh  = (const float*)d_in[7];
    const float* bih  = (const float*)d_in[8];
    const float* bhh  = (const float*)d_in[9];

    const int H = 128;
    const int N = in_sizes[0] / H;
    const int E = in_sizes[2];

    // ---- workspace layout ----
    char* w = (char*)d_ws;
    __bf16* he_mean   = (__bf16*)w;  w += (size_t)N * H * 2;
    __bf16* hsrc_mean = (__bf16*)w;  w += (size_t)N * H * 2;
    int* degi    = (int*)w;  w += (size_t)N * 4;
    int* counter = (int*)w;  w += 4;                  // contiguous with degi for one memset
    int* off     = (int*)w;  w += (size_t)N * 4;
    int* cnt     = (int*)w;  w += (size_t)N * 4;
    w = (char*)(((uintptr_t)w + 15) & ~(uintptr_t)15);
    int2* pairs  = (int2*)w; w += (size_t)E * 8;
    __bf16* wmsg_bf = (__bf16*)w;
    __bf16* wih_bf  = wmsg_bf + 2 * 256 * 384;
    __bf16* whh_bf  = wih_bf  + 2 * 384 * 256;

    hipMemsetAsync(degi, 0, ((size_t)N + 1) * 4, stream);   // degi + counter

    const int n_msg = 2 * 256 * 384, n_ih = 2 * 384 * 256, n_hh = 2 * 384 * 128;
    const int tot = n_msg + n_ih + n_hh;
    k_convert_weights<<<(tot / 4 + 255) / 256, 256, 0, stream>>>(
        Wmsg, Wih, Whh, wmsg_bf, wih_bf, whh_bf, n_msg, n_ih, n_hh);

    // ---- CSR build (disjoint-range allocation, no serial scan) ----
    k_deg<<<(E + 255) / 256, 256, 0, stream>>>(dst, degi, E);
    k_alloc<<<(N + 255) / 256, 256, 0, stream>>>(degi, off, cnt, counter, N);
    k_bucket<<<(E + 255) / 256, 256, 0, stream>>>(src, dst, off, cnt, pairs, E);

    float* out = (float*)d_out;

    // round 1: fused he+hv gather
    k_gather_both<<<(N + 3) / 4, 256, 0, stream>>>(hv, he, pairs, off, degi,
                                                   hsrc_mean, he_mean, N);
    k_fused_round<<<(N + 31) / 32, 256, 0, stream>>>(
        hv, hsrc_mean, he_mean,
        wmsg_bf, bmsg, wih_bf, whh_bf, bih, bhh, out, N);

    // round 2
    k_gather_hv<<<(N + 3) / 4, 256, 0, stream>>>(out, pairs, off, degi, hsrc_mean, N);
    k_fused_round<<<(N + 31) / 32, 256, 0, stream>>>(
        out, hsrc_mean, he_mean,
        wmsg_bf + (size_t)256 * 384, bmsg + 256,
        wih_bf + (size_t)384 * 256, whh_bf + (size_t)384 * 128,
        bih + 384, bhh + 384, out, N);
}

// Round 4
// 568.441 us; speedup vs baseline: 7.8043x; 1.0343x over previous
//
#include <hip/hip_runtime.h>
#include <hip/hip_bf16.h>

typedef __bf16 bf16x8 __attribute__((ext_vector_type(8)));
typedef __bf16 bf16x2 __attribute__((ext_vector_type(2)));
typedef float  f32x4  __attribute__((ext_vector_type(4)));

#define MFMA16(a,b,c) __builtin_amdgcn_mfma_f32_16x16x32_bf16((a),(b),(c),0,0,0)

// ---------------- weight fp32 -> bf16 conversion ----------------
__global__ void k_convert_weights(const float* __restrict__ wmsg,
                                  const float* __restrict__ wih,
                                  const float* __restrict__ whh,
                                  __bf16* __restrict__ o_msg,
                                  __bf16* __restrict__ o_ih,
                                  __bf16* __restrict__ o_hh,
                                  int n_msg, int n_ih, int n_hh) {
    int i = (blockIdx.x * 256 + threadIdx.x) * 4;
    int total = n_msg + n_ih + n_hh;
    #pragma unroll
    for (int j = 0; j < 4; ++j) {
        int idx = i + j;
        if (idx >= total) return;
        if (idx < n_msg)              o_msg[idx]               = (__bf16)wmsg[idx];
        else if (idx < n_msg + n_ih)  o_ih[idx - n_msg]        = (__bf16)wih[idx - n_msg];
        else                          o_hh[idx - n_msg - n_ih] = (__bf16)whh[idx - n_msg - n_ih];
    }
}

// ---------------- hv fp32 -> bf16 row copy ----------------
__global__ void k_convert_hv(const float* __restrict__ hv, __bf16* __restrict__ hv_bf,
                             int total8) {
    int i = blockIdx.x * 256 + threadIdx.x;
    if (i >= total8) return;
    const float4* p = (const float4*)(hv + (size_t)i * 8);
    float4 a = p[0], b = p[1];
    bf16x8 o;
    o[0] = (__bf16)a.x; o[1] = (__bf16)a.y; o[2] = (__bf16)a.z; o[3] = (__bf16)a.w;
    o[4] = (__bf16)b.x; o[5] = (__bf16)b.y; o[6] = (__bf16)b.z; o[7] = (__bf16)b.w;
    *(bf16x8*)(hv_bf + (size_t)i * 8) = o;
}

// ---------------- CSR build ----------------
__global__ void k_deg(const int* __restrict__ dst, int* __restrict__ degi, int E) {
    int e = blockIdx.x * 256 + threadIdx.x;
    if (e < E) atomicAdd(&degi[dst[e]], 1);
}

__global__ void k_alloc(const int* __restrict__ degi, int* __restrict__ off,
                        int* __restrict__ cnt, int* __restrict__ counter, int N) {
    int i = blockIdx.x * 256 + threadIdx.x;
    int lane = (int)threadIdx.x & 63;
    int v = (i < N) ? degi[i] : 0;
    int incl = v;
    #pragma unroll
    for (int d = 1; d < 64; d <<= 1) {
        int t = __shfl_up(incl, d, 64);
        if (lane >= d) incl += t;
    }
    int base = 0;
    if (lane == 63) base = atomicAdd(counter, incl);
    base = __shfl(base, 63, 64);
    if (i < N) { off[i] = base + incl - v; cnt[i] = 0; }
}

__global__ void k_bucket(const int* __restrict__ src, const int* __restrict__ dst,
                         const int* __restrict__ off, int* __restrict__ cnt,
                         int2* __restrict__ pairs, int E) {
    int e = blockIdx.x * 256 + threadIdx.x;
    if (e < E) {
        int d = dst[e];
        int p = off[d] + atomicAdd(&cnt[d], 1);
        pairs[p] = make_int2(src[e], e);
    }
}

// ---------------- round-1 gather: mean(hv_bf[src]) and mean(he[eid]) ----------------
__global__ void k_gather_both(const __bf16* __restrict__ hv_bf, const float* __restrict__ he,
                              const int2* __restrict__ pairs,
                              const int* __restrict__ off, const int* __restrict__ degi,
                              __bf16* __restrict__ hsrc_mean, __bf16* __restrict__ he_mean,
                              int N) {
    int node = blockIdx.x * 4 + ((int)threadIdx.x >> 6);
    if (node >= N) return;
    int lane = (int)threadIdx.x & 63;
    int beg = off[node], deg = degi[node];
    int end = beg + deg;
    float h0x=0.f,h0y=0.f,h1x=0.f,h1y=0.f,h2x=0.f,h2y=0.f,h3x=0.f,h3y=0.f;
    float e0x=0.f,e0y=0.f,e1x=0.f,e1y=0.f,e2x=0.f,e2y=0.f,e3x=0.f,e3y=0.f;
    int p = beg;
    for (; p + 3 < end; p += 4) {
        int2 a = pairs[p], b = pairs[p+1], c = pairs[p+2], d = pairs[p+3];
        bf16x2 v0 = *(const bf16x2*)(hv_bf + (size_t)a.x * 128 + lane * 2);
        bf16x2 v1 = *(const bf16x2*)(hv_bf + (size_t)b.x * 128 + lane * 2);
        bf16x2 v2 = *(const bf16x2*)(hv_bf + (size_t)c.x * 128 + lane * 2);
        bf16x2 v3 = *(const bf16x2*)(hv_bf + (size_t)d.x * 128 + lane * 2);
        float2 w0 = *(const float2*)(he + (size_t)a.y * 128 + lane * 2);
        float2 w1 = *(const float2*)(he + (size_t)b.y * 128 + lane * 2);
        float2 w2 = *(const float2*)(he + (size_t)c.y * 128 + lane * 2);
        float2 w3 = *(const float2*)(he + (size_t)d.y * 128 + lane * 2);
        h0x += (float)v0[0]; h0y += (float)v0[1]; h1x += (float)v1[0]; h1y += (float)v1[1];
        h2x += (float)v2[0]; h2y += (float)v2[1]; h3x += (float)v3[0]; h3y += (float)v3[1];
        e0x += w0.x; e0y += w0.y; e1x += w1.x; e1y += w1.y;
        e2x += w2.x; e2y += w2.y; e3x += w3.x; e3y += w3.y;
    }
    for (; p < end; ++p) {
        int2 a = pairs[p];
        bf16x2 v0 = *(const bf16x2*)(hv_bf + (size_t)a.x * 128 + lane * 2);
        float2 w0 = *(const float2*)(he + (size_t)a.y * 128 + lane * 2);
        h0x += (float)v0[0]; h0y += (float)v0[1];
        e0x += w0.x; e0y += w0.y;
    }
    float s = 1.0f / fmaxf((float)deg, 1.0f);
    bf16x2 oh; oh[0] = (__bf16)((h0x+h1x+h2x+h3x) * s); oh[1] = (__bf16)((h0y+h1y+h2y+h3y) * s);
    bf16x2 oe; oe[0] = (__bf16)((e0x+e1x+e2x+e3x) * s); oe[1] = (__bf16)((e0y+e1y+e2y+e3y) * s);
    *(bf16x2*)(hsrc_mean + (size_t)node * 128 + lane * 2) = oh;
    *(bf16x2*)(he_mean   + (size_t)node * 128 + lane * 2) = oe;
}

// ---------------- round-2 gather: mean(hv_bf[src]) only ----------------
__global__ void k_gather_hv(const __bf16* __restrict__ hv_bf, const int2* __restrict__ pairs,
                            const int* __restrict__ off, const int* __restrict__ degi,
                            __bf16* __restrict__ hsrc_mean, int N) {
    int node = blockIdx.x * 4 + ((int)threadIdx.x >> 6);
    if (node >= N) return;
    int lane = (int)threadIdx.x & 63;
    int beg = off[node], deg = degi[node];
    int end = beg + deg;
    float a0x=0.f,a0y=0.f,a1x=0.f,a1y=0.f,a2x=0.f,a2y=0.f,a3x=0.f,a3y=0.f;
    int p = beg;
    for (; p + 3 < end; p += 4) {
        int2 pa = pairs[p], pb = pairs[p+1], pc = pairs[p+2], pd = pairs[p+3];
        bf16x2 v0 = *(const bf16x2*)(hv_bf + (size_t)pa.x * 128 + lane * 2);
        bf16x2 v1 = *(const bf16x2*)(hv_bf + (size_t)pb.x * 128 + lane * 2);
        bf16x2 v2 = *(const bf16x2*)(hv_bf + (size_t)pc.x * 128 + lane * 2);
        bf16x2 v3 = *(const bf16x2*)(hv_bf + (size_t)pd.x * 128 + lane * 2);
        a0x += (float)v0[0]; a0y += (float)v0[1]; a1x += (float)v1[0]; a1y += (float)v1[1];
        a2x += (float)v2[0]; a2y += (float)v2[1]; a3x += (float)v3[0]; a3y += (float)v3[1];
    }
    for (; p < end; ++p) {
        int2 pa = pairs[p];
        bf16x2 v0 = *(const bf16x2*)(hv_bf + (size_t)pa.x * 128 + lane * 2);
        a0x += (float)v0[0]; a0y += (float)v0[1];
    }
    float s = 1.0f / fmaxf((float)deg, 1.0f);
    bf16x2 o; o[0] = (__bf16)((a0x+a1x+a2x+a3x) * s); o[1] = (__bf16)((a0y+a1y+a2y+a3y) * s);
    *(bf16x2*)(hsrc_mean + (size_t)node * 128 + lane * 2) = o;
}

// ---------------- fused round: x-build + 3 GEMMs (bf16 MFMA) + GRU epilogue ----------
template<bool WRITE_BF>
__launch_bounds__(256)
__global__ void k_fused_round(
    const float* __restrict__ hv_hold,     // [N,128] f32 (GRU hold; may alias hv_out)
    __bf16* __restrict__ hv_bf,            // [N,128] bf16 (xs source; epilogue-updated if WRITE_BF)
    const __bf16* __restrict__ hsrc_mean,  // [N,128] bf16
    const __bf16* __restrict__ he_mean,    // [N,128] bf16
    const __bf16* __restrict__ Wmsg,       // [256,384]
    const float* __restrict__ bmsg,        // [256]
    const __bf16* __restrict__ Wih,        // [384,256]
    const __bf16* __restrict__ Whh,        // [384,128]
    const float* __restrict__ bih,         // [384]
    const float* __restrict__ bhh,         // [384]
    float* __restrict__ hv_out, int N)
{
    __shared__ __bf16 xs[32][392];   // 384 + 8 pad
    __shared__ __bf16 as[32][264];   // 256 + 8 pad

    const int tid = threadIdx.x;
    const int m0  = blockIdx.x * 32;

    // ---- build x = [hv_bf | hsrc_mean | he_mean], all bf16x8 copies ----
    for (int idx = tid; idx < 32 * 48; idx += 256) {
        int row = idx / 48;
        int c   = idx - row * 48;
        int part = c >> 4;                  // 0: hv, 1: hsrc, 2: he
        int c8   = (c & 15) * 8;
        int node = m0 + row;
        const __bf16* base = (part == 0) ? hv_bf : ((part == 1) ? hsrc_mean : he_mean);
        bf16x8 v = {};
        if (node < N) v = *(const bf16x8*)(base + (size_t)node * 128 + c8);
        *(bf16x8*)&xs[row][part * 128 + c8] = v;
    }
    __syncthreads();

    const int wave = tid >> 6;
    const int lane = tid & 63;
    const int lr = lane & 15;
    const int lk = lane >> 4;

    // ---- GEMM1: a = x @ Wmsg^T ----
    f32x4 acc1[2][4] = {};
    for (int k0 = 0; k0 < 384; k0 += 32) {
        bf16x8 a0 = *(const bf16x8*)&xs[lr][k0 + lk * 8];
        bf16x8 a1 = *(const bf16x8*)&xs[16 + lr][k0 + lk * 8];
        #pragma unroll
        for (int c = 0; c < 4; ++c) {
            const __bf16* wp = Wmsg + (size_t)(wave * 64 + c * 16 + lr) * 384 + k0 + lk * 8;
            bf16x8 b = *(const bf16x8*)wp;
            acc1[0][c] = MFMA16(a0, b, acc1[0][c]);
            acc1[1][c] = MFMA16(a1, b, acc1[1][c]);
        }
    }
    #pragma unroll
    for (int mf = 0; mf < 2; ++mf) {
        #pragma unroll
        for (int c = 0; c < 4; ++c) {
            int n = wave * 64 + c * 16 + lr;
            float bias = bmsg[n];
            #pragma unroll
            for (int r = 0; r < 4; ++r) {
                int m = mf * 16 + lk * 4 + r;
                as[m][n] = (__bf16)(acc1[mf][c][r] + bias);
            }
        }
    }
    __syncthreads();

    // ---- GEMM2: gi = a @ Wih^T ----
    f32x4 acc2[2][6] = {};
    for (int k0 = 0; k0 < 256; k0 += 32) {
        bf16x8 a0 = *(const bf16x8*)&as[lr][k0 + lk * 8];
        bf16x8 a1 = *(const bf16x8*)&as[16 + lr][k0 + lk * 8];
        #pragma unroll
        for (int q = 0; q < 6; ++q) {
            int o = (q >> 1) * 128 + wave * 32 + (q & 1) * 16 + lr;
            bf16x8 b = *(const bf16x8*)(Wih + (size_t)o * 256 + k0 + lk * 8);
            acc2[0][q] = MFMA16(a0, b, acc2[0][q]);
            acc2[1][q] = MFMA16(a1, b, acc2[1][q]);
        }
    }

    // ---- GEMM3: gh = hv @ Whh^T ----
    f32x4 acc3[2][6] = {};
    for (int k0 = 0; k0 < 128; k0 += 32) {
        bf16x8 a0 = *(const bf16x8*)&xs[lr][k0 + lk * 8];
        bf16x8 a1 = *(const bf16x8*)&xs[16 + lr][k0 + lk * 8];
        #pragma unroll
        for (int q = 0; q < 6; ++q) {
            int o = (q >> 1) * 128 + wave * 32 + (q & 1) * 16 + lr;
            bf16x8 b = *(const bf16x8*)(Whh + (size_t)o * 128 + k0 + lk * 8);
            acc3[0][q] = MFMA16(a0, b, acc3[0][q]);
            acc3[1][q] = MFMA16(a1, b, acc3[1][q]);
        }
    }

    // ---- GRU epilogue ----
    #pragma unroll
    for (int mf = 0; mf < 2; ++mf) {
        #pragma unroll
        for (int j = 0; j < 2; ++j) {
            int hcol = wave * 32 + j * 16 + lr;
            float b_ir = bih[hcol],       b_hr = bhh[hcol];
            float b_iz = bih[128 + hcol], b_hz = bhh[128 + hcol];
            float b_in = bih[256 + hcol], b_hn = bhh[256 + hcol];
            #pragma unroll
            for (int r = 0; r < 4; ++r) {
                int m = mf * 16 + lk * 4 + r;
                int node = m0 + m;
                if (node < N) {
                    float ir = acc2[mf][0 + j][r] + b_ir, hr = acc3[mf][0 + j][r] + b_hr;
                    float iz = acc2[mf][2 + j][r] + b_iz, hz = acc3[mf][2 + j][r] + b_hz;
                    float in_ = acc2[mf][4 + j][r] + b_in, hn = acc3[mf][4 + j][r] + b_hn;
                    float rg = 1.f / (1.f + __expf(-(ir + hr)));
                    float zg = 1.f / (1.f + __expf(-(iz + hz)));
                    float ng = tanhf(in_ + rg * hn);
                    float hold = hv_hold[(size_t)node * 128 + hcol];
                    float hnew = (1.f - zg) * ng + zg * hold;
                    hv_out[(size_t)node * 128 + hcol] = hnew;
                    if (WRITE_BF) hv_bf[(size_t)node * 128 + hcol] = (__bf16)hnew;
                }
            }
        }
    }
}

extern "C" void kernel_launch(void* const* d_in, const int* in_sizes, int n_in,
                              void* d_out, int out_size, void* d_ws, size_t ws_size,
                              hipStream_t stream)
{
    const float* hv   = (const float*)d_in[0];
    const float* he   = (const float*)d_in[1];
    const int*   src  = (const int*)d_in[2];
    const int*   dst  = (const int*)d_in[3];
    const float* Wmsg = (const float*)d_in[4];
    const float* bmsg = (const float*)d_in[5];
    const float* Wih  = (const float*)d_in[6];
    const float* Whh  = (const float*)d_in[7];
    const float* bih  = (const float*)d_in[8];
    const float* bhh  = (const float*)d_in[9];

    const int H = 128;
    const int N = in_sizes[0] / H;
    const int E = in_sizes[2];

    // ---- workspace layout (~46 MB) ----
    char* w = (char*)d_ws;
    __bf16* he_mean   = (__bf16*)w;  w += (size_t)N * H * 2;
    __bf16* hsrc_mean = (__bf16*)w;  w += (size_t)N * H * 2;
    __bf16* hv_bf     = (__bf16*)w;  w += (size_t)N * H * 2;
    int* degi    = (int*)w;  w += (size_t)N * 4;
    int* counter = (int*)w;  w += 4;
    int* off     = (int*)w;  w += (size_t)N * 4;
    int* cnt     = (int*)w;  w += (size_t)N * 4;
    w = (char*)(((uintptr_t)w + 15) & ~(uintptr_t)15);
    int2* pairs  = (int2*)w; w += (size_t)E * 8;
    __bf16* wmsg_bf = (__bf16*)w;
    __bf16* wih_bf  = wmsg_bf + 2 * 256 * 384;
    __bf16* whh_bf  = wih_bf  + 2 * 384 * 256;

    hipMemsetAsync(degi, 0, ((size_t)N + 1) * 4, stream);   // degi + counter

    const int n_msg = 2 * 256 * 384, n_ih = 2 * 384 * 256, n_hh = 2 * 384 * 128;
    const int tot = n_msg + n_ih + n_hh;
    k_convert_weights<<<(tot / 4 + 255) / 256, 256, 0, stream>>>(
        Wmsg, Wih, Whh, wmsg_bf, wih_bf, whh_bf, n_msg, n_ih, n_hh);
    k_convert_hv<<<(N * H / 8 + 255) / 256, 256, 0, stream>>>(hv, hv_bf, N * H / 8);

    // ---- CSR build ----
    k_deg<<<(E + 255) / 256, 256, 0, stream>>>(dst, degi, E);
    k_alloc<<<(N + 255) / 256, 256, 0, stream>>>(degi, off, cnt, counter, N);
    k_bucket<<<(E + 255) / 256, 256, 0, stream>>>(src, dst, off, cnt, pairs, E);

    float* out = (float*)d_out;

    // round 1
    k_gather_both<<<(N + 3) / 4, 256, 0, stream>>>(hv_bf, he, pairs, off, degi,
                                                   hsrc_mean, he_mean, N);
    k_fused_round<true><<<(N + 31) / 32, 256, 0, stream>>>(
        hv, hv_bf, hsrc_mean, he_mean,
        wmsg_bf, bmsg, wih_bf, whh_bf, bih, bhh, out, N);

    // round 2 (hv_bf now holds bf16(hv_new); out updated in place)
    k_gather_hv<<<(N + 3) / 4, 256, 0, stream>>>(hv_bf, pairs, off, degi, hsrc_mean, N);
    k_fused_round<false><<<(N + 31) / 32, 256, 0, stream>>>(
        out, hv_bf, hsrc_mean, he_mean,
        wmsg_bf + (size_t)256 * 384, bmsg + 256,
        wih_bf + (size_t)384 * 256, whh_bf + (size_t)384 * 128,
        bih + 384, bhh + 384, out, N);
}

// Round 5
// 529.785 us; speedup vs baseline: 8.3738x; 1.0730x over previous
//
#include <hip/hip_runtime.h>
#include <hip/hip_bf16.h>

typedef __bf16 bf16x8 __attribute__((ext_vector_type(8)));
typedef __bf16 bf16x2 __attribute__((ext_vector_type(2)));
typedef float  f32x4  __attribute__((ext_vector_type(4)));

#define MFMA16(a,b,c) __builtin_amdgcn_mfma_f32_16x16x32_bf16((a),(b),(c),0,0,0)

// ---------------- weight fp32 -> bf16 conversion ----------------
__global__ void k_convert_weights(const float* __restrict__ wmsg,
                                  const float* __restrict__ wih,
                                  const float* __restrict__ whh,
                                  __bf16* __restrict__ o_msg,
                                  __bf16* __restrict__ o_ih,
                                  __bf16* __restrict__ o_hh,
                                  int n_msg, int n_ih, int n_hh) {
    int i = (blockIdx.x * 256 + threadIdx.x) * 4;
    int total = n_msg + n_ih + n_hh;
    #pragma unroll
    for (int j = 0; j < 4; ++j) {
        int idx = i + j;
        if (idx >= total) return;
        if (idx < n_msg)              o_msg[idx]               = (__bf16)wmsg[idx];
        else if (idx < n_msg + n_ih)  o_ih[idx - n_msg]        = (__bf16)wih[idx - n_msg];
        else                          o_hh[idx - n_msg - n_ih] = (__bf16)whh[idx - n_msg - n_ih];
    }
}

// ---------------- hv fp32 -> bf16 row copy ----------------
__global__ void k_convert_hv(const float* __restrict__ hv, __bf16* __restrict__ hv_bf,
                             int total8) {
    int i = blockIdx.x * 256 + threadIdx.x;
    if (i >= total8) return;
    const float4* p = (const float4*)(hv + (size_t)i * 8);
    float4 a = p[0], b = p[1];
    bf16x8 o;
    o[0] = (__bf16)a.x; o[1] = (__bf16)a.y; o[2] = (__bf16)a.z; o[3] = (__bf16)a.w;
    o[4] = (__bf16)b.x; o[5] = (__bf16)b.y; o[6] = (__bf16)b.z; o[7] = (__bf16)b.w;
    *(bf16x8*)(hv_bf + (size_t)i * 8) = o;
}

// ---------------- CSR build ----------------
__global__ void k_deg(const int* __restrict__ dst, int* __restrict__ degi, int E) {
    int e = blockIdx.x * 256 + threadIdx.x;
    if (e < E) atomicAdd(&degi[dst[e]], 1);
}

__global__ void k_alloc(const int* __restrict__ degi, int* __restrict__ off,
                        int* __restrict__ cnt, int* __restrict__ counter, int N) {
    int i = blockIdx.x * 256 + threadIdx.x;
    int lane = (int)threadIdx.x & 63;
    int v = (i < N) ? degi[i] : 0;
    int incl = v;
    #pragma unroll
    for (int d = 1; d < 64; d <<= 1) {
        int t = __shfl_up(incl, d, 64);
        if (lane >= d) incl += t;
    }
    int base = 0;
    if (lane == 63) base = atomicAdd(counter, incl);
    base = __shfl(base, 63, 64);
    if (i < N) { off[i] = base + incl - v; cnt[i] = 0; }
}

__global__ void k_bucket(const int* __restrict__ src, const int* __restrict__ dst,
                         const int* __restrict__ off, int* __restrict__ cnt,
                         int2* __restrict__ pairs, int E) {
    int e = blockIdx.x * 256 + threadIdx.x;
    if (e < E) {
        int d = dst[e];
        int p = off[d] + atomicAdd(&cnt[d], 1);
        pairs[p] = make_int2(src[e], e);
    }
}

// ---------------- round-1 gather: mean(hv_bf[src]) and mean(he[eid]) ----------------
__global__ void k_gather_both(const __bf16* __restrict__ hv_bf, const float* __restrict__ he,
                              const int2* __restrict__ pairs,
                              const int* __restrict__ off, const int* __restrict__ degi,
                              __bf16* __restrict__ hsrc_mean, __bf16* __restrict__ he_mean,
                              int N) {
    int node = blockIdx.x * 4 + ((int)threadIdx.x >> 6);
    if (node >= N) return;
    int lane = (int)threadIdx.x & 63;
    int beg = off[node], deg = degi[node];
    int end = beg + deg;
    float h0x=0.f,h0y=0.f,h1x=0.f,h1y=0.f,h2x=0.f,h2y=0.f,h3x=0.f,h3y=0.f;
    float e0x=0.f,e0y=0.f,e1x=0.f,e1y=0.f,e2x=0.f,e2y=0.f,e3x=0.f,e3y=0.f;
    int p = beg;
    for (; p + 3 < end; p += 4) {
        int2 a = pairs[p], b = pairs[p+1], c = pairs[p+2], d = pairs[p+3];
        bf16x2 v0 = *(const bf16x2*)(hv_bf + (size_t)a.x * 128 + lane * 2);
        bf16x2 v1 = *(const bf16x2*)(hv_bf + (size_t)b.x * 128 + lane * 2);
        bf16x2 v2 = *(const bf16x2*)(hv_bf + (size_t)c.x * 128 + lane * 2);
        bf16x2 v3 = *(const bf16x2*)(hv_bf + (size_t)d.x * 128 + lane * 2);
        float2 w0 = *(const float2*)(he + (size_t)a.y * 128 + lane * 2);
        float2 w1 = *(const float2*)(he + (size_t)b.y * 128 + lane * 2);
        float2 w2 = *(const float2*)(he + (size_t)c.y * 128 + lane * 2);
        float2 w3 = *(const float2*)(he + (size_t)d.y * 128 + lane * 2);
        h0x += (float)v0[0]; h0y += (float)v0[1]; h1x += (float)v1[0]; h1y += (float)v1[1];
        h2x += (float)v2[0]; h2y += (float)v2[1]; h3x += (float)v3[0]; h3y += (float)v3[1];
        e0x += w0.x; e0y += w0.y; e1x += w1.x; e1y += w1.y;
        e2x += w2.x; e2y += w2.y; e3x += w3.x; e3y += w3.y;
    }
    for (; p < end; ++p) {
        int2 a = pairs[p];
        bf16x2 v0 = *(const bf16x2*)(hv_bf + (size_t)a.x * 128 + lane * 2);
        float2 w0 = *(const float2*)(he + (size_t)a.y * 128 + lane * 2);
        h0x += (float)v0[0]; h0y += (float)v0[1];
        e0x += w0.x; e0y += w0.y;
    }
    float s = 1.0f / fmaxf((float)deg, 1.0f);
    bf16x2 oh; oh[0] = (__bf16)((h0x+h1x+h2x+h3x) * s); oh[1] = (__bf16)((h0y+h1y+h2y+h3y) * s);
    bf16x2 oe; oe[0] = (__bf16)((e0x+e1x+e2x+e3x) * s); oe[1] = (__bf16)((e0y+e1y+e2y+e3y) * s);
    *(bf16x2*)(hsrc_mean + (size_t)node * 128 + lane * 2) = oh;
    *(bf16x2*)(he_mean   + (size_t)node * 128 + lane * 2) = oe;
}

// ---------------- round-2 gather: mean(hv_bf[src]) only ----------------
__global__ void k_gather_hv(const __bf16* __restrict__ hv_bf, const int2* __restrict__ pairs,
                            const int* __restrict__ off, const int* __restrict__ degi,
                            __bf16* __restrict__ hsrc_mean, int N) {
    int node = blockIdx.x * 4 + ((int)threadIdx.x >> 6);
    if (node >= N) return;
    int lane = (int)threadIdx.x & 63;
    int beg = off[node], deg = degi[node];
    int end = beg + deg;
    float a0x=0.f,a0y=0.f,a1x=0.f,a1y=0.f,a2x=0.f,a2y=0.f,a3x=0.f,a3y=0.f;
    int p = beg;
    for (; p + 3 < end; p += 4) {
        int2 pa = pairs[p], pb = pairs[p+1], pc = pairs[p+2], pd = pairs[p+3];
        bf16x2 v0 = *(const bf16x2*)(hv_bf + (size_t)pa.x * 128 + lane * 2);
        bf16x2 v1 = *(const bf16x2*)(hv_bf + (size_t)pb.x * 128 + lane * 2);
        bf16x2 v2 = *(const bf16x2*)(hv_bf + (size_t)pc.x * 128 + lane * 2);
        bf16x2 v3 = *(const bf16x2*)(hv_bf + (size_t)pd.x * 128 + lane * 2);
        a0x += (float)v0[0]; a0y += (float)v0[1]; a1x += (float)v1[0]; a1y += (float)v1[1];
        a2x += (float)v2[0]; a2y += (float)v2[1]; a3x += (float)v3[0]; a3y += (float)v3[1];
    }
    for (; p < end; ++p) {
        int2 pa = pairs[p];
        bf16x2 v0 = *(const bf16x2*)(hv_bf + (size_t)pa.x * 128 + lane * 2);
        a0x += (float)v0[0]; a0y += (float)v0[1];
    }
    float s = 1.0f / fmaxf((float)deg, 1.0f);
    bf16x2 o; o[0] = (__bf16)((a0x+a1x+a2x+a3x) * s); o[1] = (__bf16)((a0y+a1y+a2y+a3y) * s);
    *(bf16x2*)(hsrc_mean + (size_t)node * 128 + lane * 2) = o;
}

// ---------------- fused round: x-build + 3 GEMMs (bf16 MFMA) + GRU epilogue ----------
// LDS overlay: xs cols [0,384) hold x for GEMM1/GEMM3; after GEMM1 completes (barrier),
// cols [128,384) are overwritten with 'a' (GEMM1 output, 256 wide) for GEMM2.
template<bool WRITE_BF>
__launch_bounds__(256)
__global__ void k_fused_round(
    const float* __restrict__ hv_hold,     // [N,128] f32 (GRU hold; may alias hv_out)
    __bf16* __restrict__ hv_bf,            // [N,128] bf16 (xs source; epilogue-updated if WRITE_BF)
    const __bf16* __restrict__ hsrc_mean,  // [N,128] bf16
    const __bf16* __restrict__ he_mean,    // [N,128] bf16
    const __bf16* __restrict__ Wmsg,       // [256,384]
    const float* __restrict__ bmsg,        // [256]
    const __bf16* __restrict__ Wih,        // [384,256]
    const __bf16* __restrict__ Whh,        // [384,128]
    const float* __restrict__ bih,         // [384]
    const float* __restrict__ bhh,         // [384]
    float* __restrict__ hv_out, int N)
{
    __shared__ __bf16 xs[32][392];   // 384 + 8 pad; [128,384) reused for 'a' after GEMM1

    const int tid = threadIdx.x;
    const int m0  = blockIdx.x * 32;

    // ---- build x = [hv_bf | hsrc_mean | he_mean], all bf16x8 copies ----
    for (int idx = tid; idx < 32 * 48; idx += 256) {
        int row = idx / 48;
        int c   = idx - row * 48;
        int part = c >> 4;                  // 0: hv, 1: hsrc, 2: he
        int c8   = (c & 15) * 8;
        int node = m0 + row;
        const __bf16* base = (part == 0) ? hv_bf : ((part == 1) ? hsrc_mean : he_mean);
        bf16x8 v = {};
        if (node < N) v = *(const bf16x8*)(base + (size_t)node * 128 + c8);
        *(bf16x8*)&xs[row][part * 128 + c8] = v;
    }
    __syncthreads();

    const int wave = tid >> 6;
    const int lane = tid & 63;
    const int lr = lane & 15;
    const int lk = lane >> 4;

    // ---- GEMM1: a = x @ Wmsg^T ----
    f32x4 acc1[2][4] = {};
    #pragma unroll 2
    for (int k0 = 0; k0 < 384; k0 += 32) {
        bf16x8 a0 = *(const bf16x8*)&xs[lr][k0 + lk * 8];
        bf16x8 a1 = *(const bf16x8*)&xs[16 + lr][k0 + lk * 8];
        #pragma unroll
        for (int c = 0; c < 4; ++c) {
            const __bf16* wp = Wmsg + (size_t)(wave * 64 + c * 16 + lr) * 384 + k0 + lk * 8;
            bf16x8 b = *(const bf16x8*)wp;
            acc1[0][c] = MFMA16(a0, b, acc1[0][c]);
            acc1[1][c] = MFMA16(a1, b, acc1[1][c]);
        }
    }
    __syncthreads();    // all waves done reading xs[*][128..383] before overlay write

    // ---- write a (+bias) into xs[*][128 + n] ----
    #pragma unroll
    for (int mf = 0; mf < 2; ++mf) {
        #pragma unroll
        for (int c = 0; c < 4; ++c) {
            int n = wave * 64 + c * 16 + lr;
            float bias = bmsg[n];
            #pragma unroll
            for (int r = 0; r < 4; ++r) {
                int m = mf * 16 + lk * 4 + r;
                xs[m][128 + n] = (__bf16)(acc1[mf][c][r] + bias);
            }
        }
    }
    __syncthreads();

    // ---- GEMM3: gh = hv @ Whh^T  (xs cols [0,128), untouched by overlay) ----
    f32x4 acc3[2][6] = {};
    #pragma unroll 2
    for (int k0 = 0; k0 < 128; k0 += 32) {
        bf16x8 a0 = *(const bf16x8*)&xs[lr][k0 + lk * 8];
        bf16x8 a1 = *(const bf16x8*)&xs[16 + lr][k0 + lk * 8];
        #pragma unroll
        for (int q = 0; q < 6; ++q) {
            int o = (q >> 1) * 128 + wave * 32 + (q & 1) * 16 + lr;
            bf16x8 b = *(const bf16x8*)(Whh + (size_t)o * 128 + k0 + lk * 8);
            acc3[0][q] = MFMA16(a0, b, acc3[0][q]);
            acc3[1][q] = MFMA16(a1, b, acc3[1][q]);
        }
    }

    // ---- GEMM2: gi = a @ Wih^T  (a lives in xs cols [128,384)) ----
    f32x4 acc2[2][6] = {};
    #pragma unroll 2
    for (int k0 = 0; k0 < 256; k0 += 32) {
        bf16x8 a0 = *(const bf16x8*)&xs[lr][128 + k0 + lk * 8];
        bf16x8 a1 = *(const bf16x8*)&xs[16 + lr][128 + k0 + lk * 8];
        #pragma unroll
        for (int q = 0; q < 6; ++q) {
            int o = (q >> 1) * 128 + wave * 32 + (q & 1) * 16 + lr;
            bf16x8 b = *(const bf16x8*)(Wih + (size_t)o * 256 + k0 + lk * 8);
            acc2[0][q] = MFMA16(a0, b, acc2[0][q]);
            acc2[1][q] = MFMA16(a1, b, acc2[1][q]);
        }
    }

    // ---- GRU epilogue ----
    #pragma unroll
    for (int mf = 0; mf < 2; ++mf) {
        #pragma unroll
        for (int j = 0; j < 2; ++j) {
            int hcol = wave * 32 + j * 16 + lr;
            float b_ir = bih[hcol],       b_hr = bhh[hcol];
            float b_iz = bih[128 + hcol], b_hz = bhh[128 + hcol];
            float b_in = bih[256 + hcol], b_hn = bhh[256 + hcol];
            #pragma unroll
            for (int r = 0; r < 4; ++r) {
                int m = mf * 16 + lk * 4 + r;
                int node = m0 + m;
                if (node < N) {
                    float ir = acc2[mf][0 + j][r] + b_ir, hr = acc3[mf][0 + j][r] + b_hr;
                    float iz = acc2[mf][2 + j][r] + b_iz, hz = acc3[mf][2 + j][r] + b_hz;
                    float in_ = acc2[mf][4 + j][r] + b_in, hn = acc3[mf][4 + j][r] + b_hn;
                    float rg = 1.f / (1.f + __expf(-(ir + hr)));
                    float zg = 1.f / (1.f + __expf(-(iz + hz)));
                    float ng = tanhf(in_ + rg * hn);
                    float hold = hv_hold[(size_t)node * 128 + hcol];
                    float hnew = (1.f - zg) * ng + zg * hold;
                    hv_out[(size_t)node * 128 + hcol] = hnew;
                    if (WRITE_BF) hv_bf[(size_t)node * 128 + hcol] = (__bf16)hnew;
                }
            }
        }
    }
}

extern "C" void kernel_launch(void* const* d_in, const int* in_sizes, int n_in,
                              void* d_out, int out_size, void* d_ws, size_t ws_size,
                              hipStream_t stream)
{
    const float* hv   = (const float*)d_in[0];
    const float* he   = (const float*)d_in[1];
    const int*   src  = (const int*)d_in[2];
    const int*   dst  = (const int*)d_in[3];
    const float* Wmsg = (const float*)d_in[4];
    const float* bmsg = (const float*)d_in[5];
    const float* Wih  = (const float*)d_in[6];
    const float* Whh  = (const float*)d_in[7];
    const float* bih  = (const float*)d_in[8];
    const float* bhh  = (const float*)d_in[9];

    const int H = 128;
    const int N = in_sizes[0] / H;
    const int E = in_sizes[2];

    // ---- workspace layout (~46 MB) ----
    char* w = (char*)d_ws;
    __bf16* he_mean   = (__bf16*)w;  w += (size_t)N * H * 2;
    __bf16* hsrc_mean = (__bf16*)w;  w += (size_t)N * H * 2;
    __bf16* hv_bf     = (__bf16*)w;  w += (size_t)N * H * 2;
    int* degi    = (int*)w;  w += (size_t)N * 4;
    int* counter = (int*)w;  w += 4;
    int* off     = (int*)w;  w += (size_t)N * 4;
    int* cnt     = (int*)w;  w += (size_t)N * 4;
    w = (char*)(((uintptr_t)w + 15) & ~(uintptr_t)15);
    int2* pairs  = (int2*)w; w += (size_t)E * 8;
    __bf16* wmsg_bf = (__bf16*)w;
    __bf16* wih_bf  = wmsg_bf + 2 * 256 * 384;
    __bf16* whh_bf  = wih_bf  + 2 * 384 * 256;

    hipMemsetAsync(degi, 0, ((size_t)N + 1) * 4, stream);   // degi + counter

    const int n_msg = 2 * 256 * 384, n_ih = 2 * 384 * 256, n_hh = 2 * 384 * 128;
    const int tot = n_msg + n_ih + n_hh;
    k_convert_weights<<<(tot / 4 + 255) / 256, 256, 0, stream>>>(
        Wmsg, Wih, Whh, wmsg_bf, wih_bf, whh_bf, n_msg, n_ih, n_hh);
    k_convert_hv<<<(N * H / 8 + 255) / 256, 256, 0, stream>>>(hv, hv_bf, N * H / 8);

    // ---- CSR build ----
    k_deg<<<(E + 255) / 256, 256, 0, stream>>>(dst, degi, E);
    k_alloc<<<(N + 255) / 256, 256, 0, stream>>>(degi, off, cnt, counter, N);
    k_bucket<<<(E + 255) / 256, 256, 0, stream>>>(src, dst, off, cnt, pairs, E);

    float* out = (float*)d_out;

    // round 1
    k_gather_both<<<(N + 3) / 4, 256, 0, stream>>>(hv_bf, he, pairs, off, degi,
                                                   hsrc_mean, he_mean, N);
    k_fused_round<true><<<(N + 31) / 32, 256, 0, stream>>>(
        hv, hv_bf, hsrc_mean, he_mean,
        wmsg_bf, bmsg, wih_bf, whh_bf, bih, bhh, out, N);

    // round 2 (hv_bf now holds bf16(hv_new); out updated in place)
    k_gather_hv<<<(N + 3) / 4, 256, 0, stream>>>(hv_bf, pairs, off, degi, hsrc_mean, N);
    k_fused_round<false><<<(N + 31) / 32, 256, 0, stream>>>(
        out, hv_bf, hsrc_mean, he_mean,
        wmsg_bf + (size_t)256 * 384, bmsg + 256,
        wih_bf + (size_t)384 * 256, whh_bf + (size_t)384 * 128,
        bih + 384, bhh + 384, out, N);
}

// Round 6
// 505.226 us; speedup vs baseline: 8.7808x; 1.0486x over previous
//
#include <hip/hip_runtime.h>
#include <hip/hip_bf16.h>

typedef __bf16 bf16x8 __attribute__((ext_vector_type(8)));
typedef __bf16 bf16x2 __attribute__((ext_vector_type(2)));
typedef float  f32x4  __attribute__((ext_vector_type(4)));

#define MFMA16(a,b,c) __builtin_amdgcn_mfma_f32_16x16x32_bf16((a),(b),(c),0,0,0)

// ---------------- weight prepack fp32 -> bf16 ----------------
// wmsg_bf : [T][256][384]  = W_msg (straight copy)
// wrz_bf  : [T][256][384]  row o = [Whh[o][0:128] | Wih[o][0:256]]  (r,z gate rows, o in 0..255)
// win_bf  : [T][128][256]  row j = Wih[256+j]
// whn_bf  : [T][128][128]  row j = Whh[256+j]
__global__ void k_prepack_weights(const float* __restrict__ wmsg,
                                  const float* __restrict__ wih,
                                  const float* __restrict__ whh,
                                  __bf16* __restrict__ o_msg,
                                  __bf16* __restrict__ o_rz,
                                  __bf16* __restrict__ o_in,
                                  __bf16* __restrict__ o_hn) {
    const int C1 = 2 * 256 * 384;            // wmsg
    const int C2 = C1 + 2 * 256 * 384;       // wrz
    const int C3 = C2 + 2 * 128 * 256;       // win
    const int C4 = C3 + 2 * 128 * 128;       // whn
    int i = blockIdx.x * 256 + threadIdx.x;
    if (i >= C4) return;
    if (i < C1) {
        o_msg[i] = (__bf16)wmsg[i];
    } else if (i < C2) {
        int p = i - C1;
        int t = p / 98304, rem = p % 98304;
        int o = rem / 384, c = rem % 384;
        float v = (c < 128) ? whh[t * 49152 + o * 128 + c]
                            : wih[t * 98304 + o * 256 + (c - 128)];
        o_rz[p] = (__bf16)v;
    } else if (i < C3) {
        int p = i - C2;
        int t = p / 32768, rem = p % 32768;
        int j = rem / 256, k = rem % 256;
        o_in[p] = (__bf16)wih[t * 98304 + (256 + j) * 256 + k];
    } else {
        int p = i - C3;
        int t = p / 16384, rem = p % 16384;
        int j = rem / 128, k = rem % 128;
        o_hn[p] = (__bf16)whh[t * 49152 + (256 + j) * 128 + k];
    }
}

// ---------------- hv fp32 -> bf16 row copy ----------------
__global__ void k_convert_hv(const float* __restrict__ hv, __bf16* __restrict__ hv_bf,
                             int total8) {
    int i = blockIdx.x * 256 + threadIdx.x;
    if (i >= total8) return;
    const float4* p = (const float4*)(hv + (size_t)i * 8);
    float4 a = p[0], b = p[1];
    bf16x8 o;
    o[0] = (__bf16)a.x; o[1] = (__bf16)a.y; o[2] = (__bf16)a.z; o[3] = (__bf16)a.w;
    o[4] = (__bf16)b.x; o[5] = (__bf16)b.y; o[6] = (__bf16)b.z; o[7] = (__bf16)b.w;
    *(bf16x8*)(hv_bf + (size_t)i * 8) = o;
}

// ---------------- CSR build ----------------
__global__ void k_deg(const int* __restrict__ dst, int* __restrict__ degi, int E) {
    int e = blockIdx.x * 256 + threadIdx.x;
    if (e < E) atomicAdd(&degi[dst[e]], 1);
}

__global__ void k_alloc(const int* __restrict__ degi, int* __restrict__ off,
                        int* __restrict__ cnt, int* __restrict__ counter, int N) {
    int i = blockIdx.x * 256 + threadIdx.x;
    int lane = (int)threadIdx.x & 63;
    int v = (i < N) ? degi[i] : 0;
    int incl = v;
    #pragma unroll
    for (int d = 1; d < 64; d <<= 1) {
        int t = __shfl_up(incl, d, 64);
        if (lane >= d) incl += t;
    }
    int base = 0;
    if (lane == 63) base = atomicAdd(counter, incl);
    base = __shfl(base, 63, 64);
    if (i < N) { off[i] = base + incl - v; cnt[i] = 0; }
}

__global__ void k_bucket(const int* __restrict__ src, const int* __restrict__ dst,
                         const int* __restrict__ off, int* __restrict__ cnt,
                         int2* __restrict__ pairs, int E) {
    int e = blockIdx.x * 256 + threadIdx.x;
    if (e < E) {
        int d = dst[e];
        int p = off[d] + atomicAdd(&cnt[d], 1);
        pairs[p] = make_int2(src[e], e);
    }
}

// ---------------- round-1 gather: mean(hv_bf[src]) and mean(he[eid]) ----------------
__global__ void k_gather_both(const __bf16* __restrict__ hv_bf, const float* __restrict__ he,
                              const int2* __restrict__ pairs,
                              const int* __restrict__ off, const int* __restrict__ degi,
                              __bf16* __restrict__ hsrc_mean, __bf16* __restrict__ he_mean,
                              int N) {
    int node = blockIdx.x * 4 + ((int)threadIdx.x >> 6);
    if (node >= N) return;
    int lane = (int)threadIdx.x & 63;
    int beg = off[node], deg = degi[node];
    int end = beg + deg;
    float h0x=0.f,h0y=0.f,h1x=0.f,h1y=0.f,h2x=0.f,h2y=0.f,h3x=0.f,h3y=0.f;
    float e0x=0.f,e0y=0.f,e1x=0.f,e1y=0.f,e2x=0.f,e2y=0.f,e3x=0.f,e3y=0.f;
    int p = beg;
    for (; p + 3 < end; p += 4) {
        int2 a = pairs[p], b = pairs[p+1], c = pairs[p+2], d = pairs[p+3];
        bf16x2 v0 = *(const bf16x2*)(hv_bf + (size_t)a.x * 128 + lane * 2);
        bf16x2 v1 = *(const bf16x2*)(hv_bf + (size_t)b.x * 128 + lane * 2);
        bf16x2 v2 = *(const bf16x2*)(hv_bf + (size_t)c.x * 128 + lane * 2);
        bf16x2 v3 = *(const bf16x2*)(hv_bf + (size_t)d.x * 128 + lane * 2);
        float2 w0 = *(const float2*)(he + (size_t)a.y * 128 + lane * 2);
        float2 w1 = *(const float2*)(he + (size_t)b.y * 128 + lane * 2);
        float2 w2 = *(const float2*)(he + (size_t)c.y * 128 + lane * 2);
        float2 w3 = *(const float2*)(he + (size_t)d.y * 128 + lane * 2);
        h0x += (float)v0[0]; h0y += (float)v0[1]; h1x += (float)v1[0]; h1y += (float)v1[1];
        h2x += (float)v2[0]; h2y += (float)v2[1]; h3x += (float)v3[0]; h3y += (float)v3[1];
        e0x += w0.x; e0y += w0.y; e1x += w1.x; e1y += w1.y;
        e2x += w2.x; e2y += w2.y; e3x += w3.x; e3y += w3.y;
    }
    for (; p < end; ++p) {
        int2 a = pairs[p];
        bf16x2 v0 = *(const bf16x2*)(hv_bf + (size_t)a.x * 128 + lane * 2);
        float2 w0 = *(const float2*)(he + (size_t)a.y * 128 + lane * 2);
        h0x += (float)v0[0]; h0y += (float)v0[1];
        e0x += w0.x; e0y += w0.y;
    }
    float s = 1.0f / fmaxf((float)deg, 1.0f);
    bf16x2 oh; oh[0] = (__bf16)((h0x+h1x+h2x+h3x) * s); oh[1] = (__bf16)((h0y+h1y+h2y+h3y) * s);
    bf16x2 oe; oe[0] = (__bf16)((e0x+e1x+e2x+e3x) * s); oe[1] = (__bf16)((e0y+e1y+e2y+e3y) * s);
    *(bf16x2*)(hsrc_mean + (size_t)node * 128 + lane * 2) = oh;
    *(bf16x2*)(he_mean   + (size_t)node * 128 + lane * 2) = oe;
}

// ---------------- round-2 gather: mean(hv_bf[src]) only ----------------
__global__ void k_gather_hv(const __bf16* __restrict__ hv_bf, const int2* __restrict__ pairs,
                            const int* __restrict__ off, const int* __restrict__ degi,
                            __bf16* __restrict__ hsrc_mean, int N) {
    int node = blockIdx.x * 4 + ((int)threadIdx.x >> 6);
    if (node >= N) return;
    int lane = (int)threadIdx.x & 63;
    int beg = off[node], deg = degi[node];
    int end = beg + deg;
    float a0x=0.f,a0y=0.f,a1x=0.f,a1y=0.f,a2x=0.f,a2y=0.f,a3x=0.f,a3y=0.f;
    int p = beg;
    for (; p + 3 < end; p += 4) {
        int2 pa = pairs[p], pb = pairs[p+1], pc = pairs[p+2], pd = pairs[p+3];
        bf16x2 v0 = *(const bf16x2*)(hv_bf + (size_t)pa.x * 128 + lane * 2);
        bf16x2 v1 = *(const bf16x2*)(hv_bf + (size_t)pb.x * 128 + lane * 2);
        bf16x2 v2 = *(const bf16x2*)(hv_bf + (size_t)pc.x * 128 + lane * 2);
        bf16x2 v3 = *(const bf16x2*)(hv_bf + (size_t)pd.x * 128 + lane * 2);
        a0x += (float)v0[0]; a0y += (float)v0[1]; a1x += (float)v1[0]; a1y += (float)v1[1];
        a2x += (float)v2[0]; a2y += (float)v2[1]; a3x += (float)v3[0]; a3y += (float)v3[1];
    }
    for (; p < end; ++p) {
        int2 pa = pairs[p];
        bf16x2 v0 = *(const bf16x2*)(hv_bf + (size_t)pa.x * 128 + lane * 2);
        a0x += (float)v0[0]; a0y += (float)v0[1];
    }
    float s = 1.0f / fmaxf((float)deg, 1.0f);
    bf16x2 o; o[0] = (__bf16)((a0x+a1x+a2x+a3x) * s); o[1] = (__bf16)((a0y+a1y+a2y+a3y) * s);
    *(bf16x2*)(hsrc_mean + (size_t)node * 128 + lane * 2) = o;
}

// ---------------- fused round ----------------
// xs = [hv(128) | a(256 after overlay)].  GEMM1: a = x @ Wmsg^T over K=384.
// Gate-fused: rz = xs[0:384) @ Wrz^T (K=384, 256 cols = [r|z]);
//             in = a @ Win^T (K=256, 128 cols); hn = hv @ Whn^T (K=128, 128 cols).
// r/z use only the sum gi+gh, so one GEMM suffices; n needs i_n, h_n separately.
template<bool WRITE_BF>
__launch_bounds__(256, 4)
__global__ void k_fused_round(
    const float* __restrict__ hv_hold,     // [N,128] f32 (GRU hold; may alias hv_out)
    __bf16* __restrict__ hv_bf,            // [N,128] bf16 (xs source; epilogue-updated if WRITE_BF)
    const __bf16* __restrict__ hsrc_mean,  // [N,128] bf16
    const __bf16* __restrict__ he_mean,    // [N,128] bf16
    const __bf16* __restrict__ Wmsg,       // [256,384]
    const float* __restrict__ bmsg,        // [256]
    const __bf16* __restrict__ Wrz,        // [256,384]
    const __bf16* __restrict__ Win,        // [128,256]
    const __bf16* __restrict__ Whn,        // [128,128]
    const float* __restrict__ bih,         // [384]
    const float* __restrict__ bhh,         // [384]
    float* __restrict__ hv_out, int N)
{
    __shared__ __bf16 xs[32][392];   // 384 + 8 pad; [128,384) reused for 'a' after GEMM1

    const int tid = threadIdx.x;
    const int m0  = blockIdx.x * 32;

    // ---- build x = [hv_bf | hsrc_mean | he_mean] ----
    for (int idx = tid; idx < 32 * 48; idx += 256) {
        int row = idx / 48;
        int c   = idx - row * 48;
        int part = c >> 4;
        int c8   = (c & 15) * 8;
        int node = m0 + row;
        const __bf16* base = (part == 0) ? hv_bf : ((part == 1) ? hsrc_mean : he_mean);
        bf16x8 v = {};
        if (node < N) v = *(const bf16x8*)(base + (size_t)node * 128 + c8);
        *(bf16x8*)&xs[row][part * 128 + c8] = v;
    }
    __syncthreads();

    const int wave = tid >> 6;
    const int lane = tid & 63;
    const int lr = lane & 15;
    const int lk = lane >> 4;

    // ---- GEMM1: a = x @ Wmsg^T ----
    f32x4 acc1[2][4] = {};
    #pragma unroll 2
    for (int k0 = 0; k0 < 384; k0 += 32) {
        bf16x8 a0 = *(const bf16x8*)&xs[lr][k0 + lk * 8];
        bf16x8 a1 = *(const bf16x8*)&xs[16 + lr][k0 + lk * 8];
        #pragma unroll
        for (int c = 0; c < 4; ++c) {
            const __bf16* wp = Wmsg + (size_t)(wave * 64 + c * 16 + lr) * 384 + k0 + lk * 8;
            bf16x8 b = *(const bf16x8*)wp;
            acc1[0][c] = MFMA16(a0, b, acc1[0][c]);
            acc1[1][c] = MFMA16(a1, b, acc1[1][c]);
        }
    }
    __syncthreads();    // all waves done reading xs[*][128..383] before overlay write

    // ---- GEMM_hn: hn = hv @ Whn^T (cols [0,128) of xs, disjoint from overlay) ----
    f32x4 acchn[2][2] = {};
    {
        // interleaves with the a-writes below (independent)
        #pragma unroll
        for (int k0 = 0; k0 < 128; k0 += 32) {
            bf16x8 a0 = *(const bf16x8*)&xs[lr][k0 + lk * 8];
            bf16x8 a1 = *(const bf16x8*)&xs[16 + lr][k0 + lk * 8];
            #pragma unroll
            for (int q = 0; q < 2; ++q) {
                int o = wave * 32 + q * 16 + lr;
                bf16x8 b = *(const bf16x8*)(Whn + (size_t)o * 128 + k0 + lk * 8);
                acchn[0][q] = MFMA16(a0, b, acchn[0][q]);
                acchn[1][q] = MFMA16(a1, b, acchn[1][q]);
            }
        }
    }

    // ---- write a (+bias) into xs[*][128 + n] ----
    #pragma unroll
    for (int mf = 0; mf < 2; ++mf) {
        #pragma unroll
        for (int c = 0; c < 4; ++c) {
            int n = wave * 64 + c * 16 + lr;
            float bias = bmsg[n];
            #pragma unroll
            for (int r = 0; r < 4; ++r) {
                int m = mf * 16 + lk * 4 + r;
                xs[m][128 + n] = (__bf16)(acc1[mf][c][r] + bias);
            }
        }
    }
    __syncthreads();

    // ---- GEMM_rz: rz = [hv|a] @ Wrz^T over K=384 ----
    f32x4 accrz[2][4] = {};
    #pragma unroll 2
    for (int k0 = 0; k0 < 384; k0 += 32) {
        bf16x8 a0 = *(const bf16x8*)&xs[lr][k0 + lk * 8];
        bf16x8 a1 = *(const bf16x8*)&xs[16 + lr][k0 + lk * 8];
        #pragma unroll
        for (int q = 0; q < 4; ++q) {
            int o = (q >> 1) * 128 + wave * 32 + (q & 1) * 16 + lr;
            bf16x8 b = *(const bf16x8*)(Wrz + (size_t)o * 384 + k0 + lk * 8);
            accrz[0][q] = MFMA16(a0, b, accrz[0][q]);
            accrz[1][q] = MFMA16(a1, b, accrz[1][q]);
        }
    }

    // ---- GEMM_in: in = a @ Win^T over K=256 ----
    f32x4 accin[2][2] = {};
    #pragma unroll 2
    for (int k0 = 0; k0 < 256; k0 += 32) {
        bf16x8 a0 = *(const bf16x8*)&xs[lr][128 + k0 + lk * 8];
        bf16x8 a1 = *(const bf16x8*)&xs[16 + lr][128 + k0 + lk * 8];
        #pragma unroll
        for (int q = 0; q < 2; ++q) {
            int o = wave * 32 + q * 16 + lr;
            bf16x8 b = *(const bf16x8*)(Win + (size_t)o * 256 + k0 + lk * 8);
            accin[0][q] = MFMA16(a0, b, accin[0][q]);
            accin[1][q] = MFMA16(a1, b, accin[1][q]);
        }
    }

    // ---- GRU epilogue ----
    #pragma unroll
    for (int mf = 0; mf < 2; ++mf) {
        #pragma unroll
        for (int j = 0; j < 2; ++j) {
            int hcol = wave * 32 + j * 16 + lr;
            float brz_r = bih[hcol]       + bhh[hcol];
            float brz_z = bih[128 + hcol] + bhh[128 + hcol];
            float b_in  = bih[256 + hcol];
            float b_hn  = bhh[256 + hcol];
            #pragma unroll
            for (int r = 0; r < 4; ++r) {
                int m = mf * 16 + lk * 4 + r;
                int node = m0 + m;
                if (node < N) {
                    float rg = 1.f / (1.f + __expf(-(accrz[mf][0 + j][r] + brz_r)));
                    float zg = 1.f / (1.f + __expf(-(accrz[mf][2 + j][r] + brz_z)));
                    float ng = tanhf(accin[mf][j][r] + b_in + rg * (acchn[mf][j][r] + b_hn));
                    float hold = hv_hold[(size_t)node * 128 + hcol];
                    float hnew = (1.f - zg) * ng + zg * hold;
                    hv_out[(size_t)node * 128 + hcol] = hnew;
                    if (WRITE_BF) hv_bf[(size_t)node * 128 + hcol] = (__bf16)hnew;
                }
            }
        }
    }
}

extern "C" void kernel_launch(void* const* d_in, const int* in_sizes, int n_in,
                              void* d_out, int out_size, void* d_ws, size_t ws_size,
                              hipStream_t stream)
{
    const float* hv   = (const float*)d_in[0];
    const float* he   = (const float*)d_in[1];
    const int*   src  = (const int*)d_in[2];
    const int*   dst  = (const int*)d_in[3];
    const float* Wmsg = (const float*)d_in[4];
    const float* bmsg = (const float*)d_in[5];
    const float* Wih  = (const float*)d_in[6];
    const float* Whh  = (const float*)d_in[7];
    const float* bih  = (const float*)d_in[8];
    const float* bhh  = (const float*)d_in[9];

    const int H = 128;
    const int N = in_sizes[0] / H;
    const int E = in_sizes[2];

    // ---- workspace layout ----
    char* w = (char*)d_ws;
    __bf16* he_mean   = (__bf16*)w;  w += (size_t)N * H * 2;
    __bf16* hsrc_mean = (__bf16*)w;  w += (size_t)N * H * 2;
    __bf16* hv_bf     = (__bf16*)w;  w += (size_t)N * H * 2;
    int* degi    = (int*)w;  w += (size_t)N * 4;
    int* counter = (int*)w;  w += 4;
    int* off     = (int*)w;  w += (size_t)N * 4;
    int* cnt     = (int*)w;  w += (size_t)N * 4;
    w = (char*)(((uintptr_t)w + 15) & ~(uintptr_t)15);
    int2* pairs  = (int2*)w; w += (size_t)E * 8;
    __bf16* wmsg_bf = (__bf16*)w;                       // [2][256][384]
    __bf16* wrz_bf  = wmsg_bf + 2 * 256 * 384;          // [2][256][384]
    __bf16* win_bf  = wrz_bf  + 2 * 256 * 384;          // [2][128][256]
    __bf16* whn_bf  = win_bf  + 2 * 128 * 256;          // [2][128][128]

    hipMemsetAsync(degi, 0, ((size_t)N + 1) * 4, stream);   // degi + counter

    const int prepack_total = 2*256*384 + 2*256*384 + 2*128*256 + 2*128*128;
    k_prepack_weights<<<(prepack_total + 255) / 256, 256, 0, stream>>>(
        Wmsg, Wih, Whh, wmsg_bf, wrz_bf, win_bf, whn_bf);
    k_convert_hv<<<(N * H / 8 + 255) / 256, 256, 0, stream>>>(hv, hv_bf, N * H / 8);

    // ---- CSR build ----
    k_deg<<<(E + 255) / 256, 256, 0, stream>>>(dst, degi, E);
    k_alloc<<<(N + 255) / 256, 256, 0, stream>>>(degi, off, cnt, counter, N);
    k_bucket<<<(E + 255) / 256, 256, 0, stream>>>(src, dst, off, cnt, pairs, E);

    float* out = (float*)d_out;

    // round 1
    k_gather_both<<<(N + 3) / 4, 256, 0, stream>>>(hv_bf, he, pairs, off, degi,
                                                   hsrc_mean, he_mean, N);
    k_fused_round<true><<<(N + 31) / 32, 256, 0, stream>>>(
        hv, hv_bf, hsrc_mean, he_mean,
        wmsg_bf, bmsg,
        wrz_bf, win_bf, whn_bf,
        bih, bhh, out, N);

    // round 2
    k_gather_hv<<<(N + 3) / 4, 256, 0, stream>>>(hv_bf, pairs, off, degi, hsrc_mean, N);
    k_fused_round<false><<<(N + 31) / 32, 256, 0, stream>>>(
        out, hv_bf, hsrc_mean, he_mean,
        wmsg_bf + (size_t)256 * 384, bmsg + 256,
        wrz_bf + (size_t)256 * 384, win_bf + (size_t)128 * 256, whn_bf + (size_t)128 * 128,
        bih + 384, bhh + 384, out, N);
}